// Round 1
// baseline (292.988 us; speedup 1.0000x reference)
//
#include <hip/hip_runtime.h>
#include <math.h>

// Problem constants (LocalAttention: B=2, T=2048, D_MODEL=512, WINDOW=32)
#define BB 2
#define TT 2048
#define CC 512
#define WIN 32
#define WSZ (2 * WIN - 1)   // 63
#define MM (BB * TT)        // 4096 rows

// ---------------------------------------------------------------------------
// GEMM (NT): C[m,n] = sum_k A[m,k] * B[n,k] + bias[n]
// A: M x K row-major, B: N x K row-major (both K-contiguous -> coalesced loads)
// Tile: BM=BN=128, BK=16, 256 threads, 8x8 micro-tile per thread.
// LDS staged transposed (k-major) so fragment reads are ds_read_b128.
// ---------------------------------------------------------------------------
#define Bb 128
#define BKk 16
#define LDP (Bb + 4)   // padded row stride (floats); +4 keeps 16B alignment, ~2-way bank conflicts on store (free)

__global__ __launch_bounds__(256) void gemm_nt_bias(
    const float* __restrict__ A, const float* __restrict__ B,
    const float* __restrict__ bias, float* __restrict__ C,
    int M, int N, int K) {
  __shared__ float As[BKk][LDP];
  __shared__ float Bs[BKk][LDP];

  const int tid = threadIdx.x;
  const int tx = tid & 15;   // N direction, 16 groups
  const int ty = tid >> 4;   // M direction, 16 groups
  const int m0 = blockIdx.y * Bb;
  const int n0 = blockIdx.x * Bb;

  float acc[8][8];
#pragma unroll
  for (int i = 0; i < 8; ++i)
#pragma unroll
    for (int j = 0; j < 8; ++j) acc[i][j] = 0.f;

  // each thread stages 2 float4 of A and 2 of B per K-step
  // float4 index f in [0,512): row = f>>2, col = (f&3)*4
  const int f0 = tid, f1 = tid + 256;
  const int r0 = f0 >> 2, c0 = (f0 & 3) << 2;
  const int r1 = f1 >> 2, c1 = (f1 & 3) << 2;

  for (int k0 = 0; k0 < K; k0 += BKk) {
    float4 a0 = *(const float4*)(A + (size_t)(m0 + r0) * K + k0 + c0);
    float4 a1 = *(const float4*)(A + (size_t)(m0 + r1) * K + k0 + c1);
    float4 b0 = *(const float4*)(B + (size_t)(n0 + r0) * K + k0 + c0);
    float4 b1 = *(const float4*)(B + (size_t)(n0 + r1) * K + k0 + c1);
    __syncthreads();
    // store transposed: As[col][row]
    As[c0 + 0][r0] = a0.x; As[c0 + 1][r0] = a0.y; As[c0 + 2][r0] = a0.z; As[c0 + 3][r0] = a0.w;
    As[c1 + 0][r1] = a1.x; As[c1 + 1][r1] = a1.y; As[c1 + 2][r1] = a1.z; As[c1 + 3][r1] = a1.w;
    Bs[c0 + 0][r0] = b0.x; Bs[c0 + 1][r0] = b0.y; Bs[c0 + 2][r0] = b0.z; Bs[c0 + 3][r0] = b0.w;
    Bs[c1 + 0][r1] = b1.x; Bs[c1 + 1][r1] = b1.y; Bs[c1 + 2][r1] = b1.z; Bs[c1 + 3][r1] = b1.w;
    __syncthreads();

#pragma unroll
    for (int kk = 0; kk < BKk; ++kk) {
      float4 av0 = *(const float4*)(&As[kk][ty * 8]);
      float4 av1 = *(const float4*)(&As[kk][ty * 8 + 4]);
      float4 bv0 = *(const float4*)(&Bs[kk][tx * 8]);
      float4 bv1 = *(const float4*)(&Bs[kk][tx * 8 + 4]);
      float a[8] = {av0.x, av0.y, av0.z, av0.w, av1.x, av1.y, av1.z, av1.w};
      float b[8] = {bv0.x, bv0.y, bv0.z, bv0.w, bv1.x, bv1.y, bv1.z, bv1.w};
#pragma unroll
      for (int i = 0; i < 8; ++i)
#pragma unroll
        for (int j = 0; j < 8; ++j) acc[i][j] += a[i] * b[j];
    }
  }

  // epilogue with bias
  float bn[8];
#pragma unroll
  for (int j = 0; j < 8; ++j) bn[j] = bias[n0 + tx * 8 + j];
#pragma unroll
  for (int i = 0; i < 8; ++i) {
    const int m = m0 + ty * 8 + i;
    float4 o0 = make_float4(acc[i][0] + bn[0], acc[i][1] + bn[1], acc[i][2] + bn[2], acc[i][3] + bn[3]);
    float4 o1 = make_float4(acc[i][4] + bn[4], acc[i][5] + bn[5], acc[i][6] + bn[6], acc[i][7] + bn[7]);
    *(float4*)(C + (size_t)m * N + n0 + tx * 8) = o0;
    *(float4*)(C + (size_t)m * N + n0 + tx * 8 + 4) = o1;
  }
}

// ---------------------------------------------------------------------------
// Banded local attention. One block (256 threads = 4 waves) per (b,t).
// qkv layout: [B*T][3*C], q at +0, k at +C, v at +2C.
// ---------------------------------------------------------------------------
__global__ __launch_bounds__(256) void attn_local(
    const float* __restrict__ qkv, float* __restrict__ out) {
  const int bt = blockIdx.x;         // 0 .. B*T-1
  const int b = bt / TT;
  const int t = bt % TT;
  const int tid = threadIdx.x;
  const int wave = tid >> 6;
  const int lane = tid & 63;

  __shared__ float q_s[CC];
  __shared__ float p_s[WSZ];

  const float* qrow = qkv + (size_t)bt * (3 * CC);
  q_s[tid] = qrow[tid];
  q_s[tid + 256] = qrow[tid + 256];
  __syncthreads();

  // scores: each wave handles j = wave, wave+4, ...
  for (int j = wave; j < WSZ; j += 4) {
    const int src = t + j - (WIN - 1);
    float s = -INFINITY;
    if (src >= 0 && src < TT) {
      const float* krow = qkv + (size_t)(b * TT + src) * (3 * CC) + CC;
      float partial = 0.f;
#pragma unroll
      for (int c = 0; c < CC; c += 64) partial += q_s[c + lane] * krow[c + lane];
#pragma unroll
      for (int off = 32; off > 0; off >>= 1) partial += __shfl_down(partial, off);
      s = partial;
    }
    if (lane == 0) p_s[j] = s;
  }
  __syncthreads();

  // softmax over 63 taps, wave 0 only
  if (tid < 64) {
    const float inv_scale = 0.044194173824159216f;  // 1/sqrt(512)
    float v = (tid < WSZ) ? p_s[tid] * inv_scale : -INFINITY;
    float m = v;
#pragma unroll
    for (int off = 32; off > 0; off >>= 1) m = fmaxf(m, __shfl_down(m, off));
    m = __shfl(m, 0);
    float e = (v == -INFINITY) ? 0.f : __expf(v - m);
    float sum = e;
#pragma unroll
    for (int off = 32; off > 0; off >>= 1) sum += __shfl_down(sum, off);
    sum = __shfl(sum, 0);
    if (tid < WSZ) p_s[tid] = e / sum;
  }
  __syncthreads();

  // out[c] = sum_j p[j] * v[src_j][c]; thread covers c = tid, tid+256
  float acc0 = 0.f, acc1 = 0.f;
  const int lo = (t - (WIN - 1) < 0) ? (WIN - 1 - t) : 0;
  const int hi = (t + WIN > TT) ? (WSZ - (t + WIN - TT)) : WSZ;
  for (int j = lo; j < hi; ++j) {
    const int src = t + j - (WIN - 1);
    const float p = p_s[j];
    const float* vrow = qkv + (size_t)(b * TT + src) * (3 * CC) + 2 * CC;
    acc0 += p * vrow[tid];
    acc1 += p * vrow[tid + 256];
  }
  out[(size_t)bt * CC + tid] = acc0;
  out[(size_t)bt * CC + tid + 256] = acc1;
}

// ---------------------------------------------------------------------------
extern "C" void kernel_launch(void* const* d_in, const int* in_sizes, int n_in,
                              void* d_out, int out_size, void* d_ws, size_t ws_size,
                              hipStream_t stream) {
  const float* x      = (const float*)d_in[0];  // (B,T,C)
  const float* w_qkv  = (const float*)d_in[1];  // (3C, C)
  const float* b_qkv  = (const float*)d_in[2];  // (3C)
  const float* w_proj = (const float*)d_in[3];  // (C, C)
  const float* b_proj = (const float*)d_in[4];  // (C)
  float* out = (float*)d_out;                   // (B,T,C)

  float* qkv  = (float*)d_ws;                       // MM x 3C
  float* attn = qkv + (size_t)MM * (3 * CC);        // MM x C

  // 1) qkv = x @ w_qkv.T + b_qkv   (M=4096, N=1536, K=512)
  {
    dim3 grid((3 * CC) / Bb, MM / Bb);
    gemm_nt_bias<<<grid, 256, 0, stream>>>(x, w_qkv, b_qkv, qkv, MM, 3 * CC, CC);
  }
  // 2) banded attention
  attn_local<<<MM, 256, 0, stream>>>(qkv, attn);
  // 3) out = attn @ w_proj.T + b_proj  (M=4096, N=512, K=512)
  {
    dim3 grid(CC / Bb, MM / Bb);
    gemm_nt_bias<<<grid, 256, 0, stream>>>(attn, w_proj, b_proj, out, MM, CC, CC);
  }
}

// Round 2
// 179.267 us; speedup vs baseline: 1.6344x; 1.6344x over previous
//
#include <hip/hip_runtime.h>
#include <math.h>

// LocalAttention: B=2, T=2048, C=512, WINDOW=32
#define BB 2
#define TT 2048
#define CC 512
#define WIN 32
#define WSZ 63            // 2*WIN-1
#define MM (BB * TT)      // 4096

typedef __attribute__((ext_vector_type(8))) short short8;
typedef __attribute__((ext_vector_type(4))) float floatx4;

__device__ inline unsigned short bf16_rn(float f) {
  unsigned u = __builtin_bit_cast(unsigned, f);
  u += 0x7fff + ((u >> 16) & 1);
  return (unsigned short)(u >> 16);
}
__device__ inline unsigned pack_bf16x2(float lo, float hi) {
  return (unsigned)bf16_rn(lo) | ((unsigned)bf16_rn(hi) << 16);
}
__device__ inline float2 bf2_to_f2(unsigned v) {
  float2 r;
  r.x = __builtin_bit_cast(float, v << 16);
  r.y = __builtin_bit_cast(float, v & 0xffff0000u);
  return r;
}

// ---------------------------------------------------------------------------
// MFMA NT GEMM: C[m,n] = sum_k A[m,k]*B[n,k] + bias[n]
// A: fp32 or bf16(ushort), B/bias: fp32; C: fp32 or bf16(ushort).
// 128x128 tile, BK=32, 4 waves (2x2), 4x4 16x16x32 frags per wave.
// ---------------------------------------------------------------------------
#define GBM 128
#define GBN 128
#define GBK 32
#define LDK 40   // padded k-stride (bf16 elems); 80B = 5*16B, frag reads ~2-way banked (free)

template <typename AT, typename OT>
__global__ __launch_bounds__(256) void gemm_nt_mfma(
    const AT* __restrict__ A, const float* __restrict__ B,
    const float* __restrict__ bias, OT* __restrict__ C,
    int M, int N, int K) {
  __shared__ __align__(16) ushort As[GBM * LDK];
  __shared__ __align__(16) ushort Bs[GBN * LDK];

  const int tid = threadIdx.x;
  const int lane = tid & 63;
  const int wave = tid >> 6;
  const int wm = (wave >> 1) * 64;
  const int wn = (wave & 1) * 64;
  const int m0 = blockIdx.y * GBM;
  const int n0 = blockIdx.x * GBN;
  const int mlane = lane & 15, mquad = lane >> 4;

  floatx4 acc[4][4];
#pragma unroll
  for (int i = 0; i < 4; ++i)
#pragma unroll
    for (int j = 0; j < 4; ++j) acc[i][j] = (floatx4){0.f, 0.f, 0.f, 0.f};

  const int srow = tid >> 1, shalf = tid & 1;  // each thread stages 16 elems of A and of B

  for (int k0 = 0; k0 < K; k0 += GBK) {
    unsigned au[8], bu[8];
    if constexpr (sizeof(AT) == 4) {  // fp32 -> bf16 RTN
      const float* ag = (const float*)A + (size_t)(m0 + srow) * K + k0 + shalf * 16;
#pragma unroll
      for (int i = 0; i < 4; ++i) {
        float4 v = ((const float4*)ag)[i];
        au[2 * i] = pack_bf16x2(v.x, v.y);
        au[2 * i + 1] = pack_bf16x2(v.z, v.w);
      }
    } else {  // already bf16
      const uint4* ag = (const uint4*)((const ushort*)A + (size_t)(m0 + srow) * K + k0 + shalf * 16);
      uint4 v0 = ag[0], v1 = ag[1];
      au[0] = v0.x; au[1] = v0.y; au[2] = v0.z; au[3] = v0.w;
      au[4] = v1.x; au[5] = v1.y; au[6] = v1.z; au[7] = v1.w;
    }
    {
      const float* bg = B + (size_t)(n0 + srow) * K + k0 + shalf * 16;
#pragma unroll
      for (int i = 0; i < 4; ++i) {
        float4 v = ((const float4*)bg)[i];
        bu[2 * i] = pack_bf16x2(v.x, v.y);
        bu[2 * i + 1] = pack_bf16x2(v.z, v.w);
      }
    }
    __syncthreads();
    *(uint4*)(&As[srow * LDK + shalf * 16]) = make_uint4(au[0], au[1], au[2], au[3]);
    *(uint4*)(&As[srow * LDK + shalf * 16 + 8]) = make_uint4(au[4], au[5], au[6], au[7]);
    *(uint4*)(&Bs[srow * LDK + shalf * 16]) = make_uint4(bu[0], bu[1], bu[2], bu[3]);
    *(uint4*)(&Bs[srow * LDK + shalf * 16 + 8]) = make_uint4(bu[4], bu[5], bu[6], bu[7]);
    __syncthreads();

    short8 af[4], bf[4];
#pragma unroll
    for (int mi = 0; mi < 4; ++mi)
      af[mi] = *(const short8*)(&As[(wm + mi * 16 + mlane) * LDK + mquad * 8]);
#pragma unroll
    for (int ni = 0; ni < 4; ++ni)
      bf[ni] = *(const short8*)(&Bs[(wn + ni * 16 + mlane) * LDK + mquad * 8]);
#pragma unroll
    for (int mi = 0; mi < 4; ++mi)
#pragma unroll
      for (int ni = 0; ni < 4; ++ni)
        acc[mi][ni] = __builtin_amdgcn_mfma_f32_16x16x32_bf16(af[mi], bf[ni], acc[mi][ni], 0, 0, 0);
  }

  // epilogue: D row = mquad*4 + r, col = mlane  (m89-verified C/D layout)
#pragma unroll
  for (int ni = 0; ni < 4; ++ni) {
    const int n = n0 + wn + ni * 16 + mlane;
    const float bn = bias[n];
#pragma unroll
    for (int mi = 0; mi < 4; ++mi) {
      const int mbase = m0 + wm + mi * 16 + mquad * 4;
#pragma unroll
      for (int r = 0; r < 4; ++r) {
        float val = acc[mi][ni][r] + bn;
        if constexpr (sizeof(OT) == 2)
          ((ushort*)C)[(size_t)(mbase + r) * N + n] = bf16_rn(val);
        else
          ((float*)C)[(size_t)(mbase + r) * N + n] = val;
      }
    }
  }
}

// ---------------------------------------------------------------------------
// Tiled banded attention, bf16 in/out. Block = 16 consecutive t (never crosses
// batch: 16 | 2048). K/V window (78 rows) staged in LDS in C-halves of 256
// to stay under 64KB static LDS. Scores accumulated into p_s across halves.
// ---------------------------------------------------------------------------
#define ATILE 16
#define ARWS 78   // ATILE + 2*(WIN-1)
#define ACH 256   // half of C
#define ACP 272   // padded half-row (elems); 544B stride = 8 banks mod 32 -> 2-way (free)

__global__ __launch_bounds__(256) void attn_tiled(
    const ushort* __restrict__ qkv, ushort* __restrict__ out) {
  __shared__ __align__(16) ushort kv_s[ARWS * ACP];  // 42432 B
  __shared__ __align__(16) ushort q_s[ATILE * ACP];  //  8704 B
  __shared__ float p_s[ATILE][64];                   //  4096 B

  const int tid = threadIdx.x;
  const int wave = tid >> 6, lane = tid & 63;
  const int g = lane >> 4, li = lane & 15;
  const int bt0 = blockIdx.x * ATILE;
  const int b = bt0 / TT, t0 = bt0 % TT;

  // ---- scores (two C-halves, partial sums accumulated in p_s) ----
  for (int h = 0; h < 2; ++h) {
    if (h) __syncthreads();
    for (int idx = tid; idx < ATILE * (ACH / 8); idx += 256) {  // stage Q half
      int row = idx >> 5, c8 = idx & 31;
      uint4 v = *(const uint4*)(qkv + (size_t)(bt0 + row) * (3 * CC) + h * ACH + c8 * 8);
      *(uint4*)(&q_s[row * ACP + c8 * 8]) = v;
    }
    for (int idx = tid; idx < ARWS * (ACH / 8); idx += 256) {  // stage K half
      int row = idx >> 5, c8 = idx & 31;
      int src = t0 - (WIN - 1) + row;
      uint4 v = make_uint4(0, 0, 0, 0);
      if (src >= 0 && src < TT)
        v = *(const uint4*)(qkv + (size_t)(b * TT + src) * (3 * CC) + CC + h * ACH + c8 * 8);
      *(uint4*)(&kv_s[row * ACP + c8 * 8]) = v;
    }
    __syncthreads();

#pragma unroll
    for (int tt = 0; tt < 4; ++tt) {
      const int tl = wave * 4 + tt;
      unsigned qv[8];
#pragma unroll
      for (int i = 0; i < 8; ++i)
        qv[i] = *(const unsigned*)(&q_s[tl * ACP + li * 2 + 32 * i]);
#pragma unroll
      for (int it = 0; it < 16; ++it) {
        const int j = it * 4 + g;         // uniform within each 16-lane group
        if (j >= WSZ) continue;
        const int row = tl + j;
        float s = 0.f;
#pragma unroll
        for (int i = 0; i < 8; ++i) {
          float2 kf = bf2_to_f2(*(const unsigned*)(&kv_s[row * ACP + li * 2 + 32 * i]));
          float2 qf = bf2_to_f2(qv[i]);
          s += qf.x * kf.x + qf.y * kf.y;
        }
        s += __shfl_xor(s, 1); s += __shfl_xor(s, 2);
        s += __shfl_xor(s, 4); s += __shfl_xor(s, 8);
        if (li == 0) {
          if (h) p_s[tl][j] += s;
          else   p_s[tl][j] = s;
        }
      }
    }
  }
  __syncthreads();

  // ---- softmax over 63 taps (mask handled here) ----
  {
    const int row = tid >> 4, li2 = tid & 15;
    const float inv_scale = 0.044194173824159216f;  // 512^-0.5
    float e[4];
    float mx = -INFINITY;
#pragma unroll
    for (int ii = 0; ii < 4; ++ii) {
      int j = li2 + 16 * ii;
      int src = t0 + row + j - (WIN - 1);
      bool valid = (j < WSZ) && (src >= 0) && (src < TT);
      e[ii] = valid ? p_s[row][j] * inv_scale : -INFINITY;
      mx = fmaxf(mx, e[ii]);
    }
    mx = fmaxf(mx, __shfl_xor(mx, 1)); mx = fmaxf(mx, __shfl_xor(mx, 2));
    mx = fmaxf(mx, __shfl_xor(mx, 4)); mx = fmaxf(mx, __shfl_xor(mx, 8));
    float sum = 0.f;
#pragma unroll
    for (int ii = 0; ii < 4; ++ii) {
      e[ii] = (e[ii] == -INFINITY) ? 0.f : __expf(e[ii] - mx);
      sum += e[ii];
    }
    sum += __shfl_xor(sum, 1); sum += __shfl_xor(sum, 2);
    sum += __shfl_xor(sum, 4); sum += __shfl_xor(sum, 8);
    const float rs = 1.f / sum;
#pragma unroll
    for (int ii = 0; ii < 4; ++ii)
      p_s[row][li2 + 16 * ii] = e[ii] * rs;
  }

  // ---- PV (two C-halves, V staged into kv_s) ----
  for (int h = 0; h < 2; ++h) {
    __syncthreads();
    for (int idx = tid; idx < ARWS * (ACH / 8); idx += 256) {
      int row = idx >> 5, c8 = idx & 31;
      int src = t0 - (WIN - 1) + row;
      uint4 v = make_uint4(0, 0, 0, 0);
      if (src >= 0 && src < TT)
        v = *(const uint4*)(qkv + (size_t)(b * TT + src) * (3 * CC) + 2 * CC + h * ACH + c8 * 8);
      *(uint4*)(&kv_s[row * ACP + c8 * 8]) = v;
    }
    __syncthreads();
    const int tl = tid >> 4, li2 = tid & 15;
    float2 a[8];
#pragma unroll
    for (int i = 0; i < 8; ++i) a[i] = make_float2(0.f, 0.f);
    for (int j = 0; j < WSZ; ++j) {
      const float p = p_s[tl][j];   // broadcast within 16-lane group
      const int row = tl + j;
#pragma unroll
      for (int i = 0; i < 8; ++i) {
        float2 vf = bf2_to_f2(*(const unsigned*)(&kv_s[row * ACP + li2 * 2 + 32 * i]));
        a[i].x += p * vf.x;
        a[i].y += p * vf.y;
      }
    }
    ushort* orow = out + (size_t)(bt0 + tl) * CC + h * ACH;
#pragma unroll
    for (int i = 0; i < 8; ++i)
      *(unsigned*)(&orow[li2 * 2 + 32 * i]) = pack_bf16x2(a[i].x, a[i].y);
  }
}

// ---------------------------------------------------------------------------
extern "C" void kernel_launch(void* const* d_in, const int* in_sizes, int n_in,
                              void* d_out, int out_size, void* d_ws, size_t ws_size,
                              hipStream_t stream) {
  const float* x      = (const float*)d_in[0];
  const float* w_qkv  = (const float*)d_in[1];
  const float* b_qkv  = (const float*)d_in[2];
  const float* w_proj = (const float*)d_in[3];
  const float* b_proj = (const float*)d_in[4];
  float* outp = (float*)d_out;

  ushort* qkv  = (ushort*)d_ws;                   // MM x 1536 bf16 (12.6 MB)
  ushort* attn = qkv + (size_t)MM * 3 * CC;       // MM x 512 bf16 (4.2 MB)

  // 1) qkv = x @ w_qkv.T + b_qkv  -> bf16
  {
    dim3 grid((3 * CC) / GBN, MM / GBM);  // 12 x 32
    gemm_nt_mfma<float, ushort><<<grid, 256, 0, stream>>>(x, w_qkv, b_qkv, qkv, MM, 3 * CC, CC);
  }
  // 2) banded attention (bf16 -> bf16)
  attn_tiled<<<MM / ATILE, 256, 0, stream>>>(qkv, attn);
  // 3) out = attn @ w_proj.T + b_proj  -> fp32
  {
    dim3 grid(CC / GBN, MM / GBM);  // 4 x 32
    gemm_nt_mfma<ushort, float><<<grid, 256, 0, stream>>>(attn, w_proj, b_proj, outp, MM, CC, CC);
  }
}

// Round 3
// 144.315 us; speedup vs baseline: 2.0302x; 1.2422x over previous
//
#include <hip/hip_runtime.h>
#include <math.h>

// LocalAttention: B=2, T=2048, C=512, WINDOW=32
#define BB 2
#define TT 2048
#define CC 512
#define WIN 32
#define WSZ 63            // 2*WIN-1
#define MM (BB * TT)      // 4096

typedef __attribute__((ext_vector_type(8))) short short8;
typedef __attribute__((ext_vector_type(4))) float floatx4;

__device__ inline unsigned short bf16_rn(float f) {
  unsigned u = __builtin_bit_cast(unsigned, f);
  u += 0x7fff + ((u >> 16) & 1);
  return (unsigned short)(u >> 16);
}
__device__ inline unsigned pack_bf16x2(float lo, float hi) {
  return (unsigned)bf16_rn(lo) | ((unsigned)bf16_rn(hi) << 16);
}
__device__ inline float2 bf2_to_f2(unsigned v) {
  float2 r;
  r.x = __builtin_bit_cast(float, v << 16);
  r.y = __builtin_bit_cast(float, v & 0xffff0000u);
  return r;
}

// ---------------------------------------------------------------------------
// Pre-convert fp32 inputs -> bf16 (x, w_qkv, w_proj). 8 elems/thread.
// ---------------------------------------------------------------------------
#define NX  (MM * CC)          // 2097152
#define NWQ (3 * CC * CC)      // 786432
#define NWP (CC * CC)          // 262144

__global__ __launch_bounds__(256) void convert_bf16(
    const float* __restrict__ x, const float* __restrict__ wq,
    const float* __restrict__ wp, ushort* __restrict__ xb,
    ushort* __restrict__ wqb, ushort* __restrict__ wpb) {
  const size_t e = ((size_t)blockIdx.x * 256 + threadIdx.x) * 8;
  const float* src;
  ushort* dst;
  size_t off;
  if (e < NX) { src = x; dst = xb; off = e; }
  else if (e < NX + NWQ) { src = wq; dst = wqb; off = e - NX; }
  else { src = wp; dst = wpb; off = e - NX - NWQ; }
  float4 v0 = ((const float4*)(src + off))[0];
  float4 v1 = ((const float4*)(src + off))[1];
  uint4 o;
  o.x = pack_bf16x2(v0.x, v0.y);
  o.y = pack_bf16x2(v0.z, v0.w);
  o.z = pack_bf16x2(v1.x, v1.y);
  o.w = pack_bf16x2(v1.z, v1.w);
  *(uint4*)(dst + off) = o;
}

// ---------------------------------------------------------------------------
// MFMA NT GEMM, all-bf16 A/B: C[m,n] = sum_k A[m,k]*B[n,k] + bias[n]
// 128x128 tile, BK=32, 4 waves (2x2), 4x4 16x16x32 frags per wave.
// ---------------------------------------------------------------------------
#define GBM 128
#define GBN 128
#define GBK 32
#define LDK 40   // padded k-stride (bf16 elems)

template <typename OT>
__global__ __launch_bounds__(256) void gemm_nt_mfma(
    const ushort* __restrict__ A, const ushort* __restrict__ B,
    const float* __restrict__ bias, OT* __restrict__ C,
    int M, int N, int K) {
  __shared__ __align__(16) ushort As[GBM * LDK];
  __shared__ __align__(16) ushort Bs[GBN * LDK];

  const int tid = threadIdx.x;
  const int lane = tid & 63;
  const int wave = tid >> 6;
  const int wm = (wave >> 1) * 64;
  const int wn = (wave & 1) * 64;
  const int m0 = blockIdx.y * GBM;
  const int n0 = blockIdx.x * GBN;
  const int mlane = lane & 15, mquad = lane >> 4;

  floatx4 acc[4][4];
#pragma unroll
  for (int i = 0; i < 4; ++i)
#pragma unroll
    for (int j = 0; j < 4; ++j) acc[i][j] = (floatx4){0.f, 0.f, 0.f, 0.f};

  const int srow = tid >> 1, shalf = tid & 1;  // 16 bf16 per thread per operand

  for (int k0 = 0; k0 < K; k0 += GBK) {
    const uint4* ag = (const uint4*)(A + (size_t)(m0 + srow) * K + k0 + shalf * 16);
    const uint4* bg = (const uint4*)(B + (size_t)(n0 + srow) * K + k0 + shalf * 16);
    uint4 a0 = ag[0], a1 = ag[1];
    uint4 b0 = bg[0], b1 = bg[1];
    __syncthreads();
    *(uint4*)(&As[srow * LDK + shalf * 16]) = a0;
    *(uint4*)(&As[srow * LDK + shalf * 16 + 8]) = a1;
    *(uint4*)(&Bs[srow * LDK + shalf * 16]) = b0;
    *(uint4*)(&Bs[srow * LDK + shalf * 16 + 8]) = b1;
    __syncthreads();

    short8 af[4], bf[4];
#pragma unroll
    for (int mi = 0; mi < 4; ++mi)
      af[mi] = *(const short8*)(&As[(wm + mi * 16 + mlane) * LDK + mquad * 8]);
#pragma unroll
    for (int ni = 0; ni < 4; ++ni)
      bf[ni] = *(const short8*)(&Bs[(wn + ni * 16 + mlane) * LDK + mquad * 8]);
#pragma unroll
    for (int mi = 0; mi < 4; ++mi)
#pragma unroll
      for (int ni = 0; ni < 4; ++ni)
        acc[mi][ni] = __builtin_amdgcn_mfma_f32_16x16x32_bf16(af[mi], bf[ni], acc[mi][ni], 0, 0, 0);
  }

  // epilogue: D row = mquad*4 + r, col = mlane
#pragma unroll
  for (int ni = 0; ni < 4; ++ni) {
    const int n = n0 + wn + ni * 16 + mlane;
    const float bn = bias[n];
#pragma unroll
    for (int mi = 0; mi < 4; ++mi) {
      const int mbase = m0 + wm + mi * 16 + mquad * 4;
#pragma unroll
      for (int r = 0; r < 4; ++r) {
        float val = acc[mi][ni][r] + bn;
        if constexpr (sizeof(OT) == 2)
          ((ushort*)C)[(size_t)(mbase + r) * N + n] = bf16_rn(val);
        else
          ((float*)C)[(size_t)(mbase + r) * N + n] = val;
      }
    }
  }
}

// ---------------------------------------------------------------------------
// Tiled banded attention, bf16 in/out. Block = 8 consecutive t (8 | 2048, never
// crosses batch). K/V window (70 rows) staged in LDS in 2 C-chunks of 256.
// LDS ~43 KB -> 2-3 blocks/CU; grid 512 blocks.
// ---------------------------------------------------------------------------
#define ATILE 8
#define ARWS 70   // ATILE + 2*(WIN-1)
#define ACH 256   // C-chunk
#define ACP 264   // padded chunk row (elems); 528B stride

__global__ __launch_bounds__(256) void attn_tiled(
    const ushort* __restrict__ qkv, ushort* __restrict__ out) {
  __shared__ __align__(16) ushort kv_s[ARWS * ACP];  // 36960 B
  __shared__ __align__(16) ushort q_s[ATILE * ACP];  //  4224 B
  __shared__ float p_s[ATILE][64];                   //  2048 B

  const int tid = threadIdx.x;
  const int wave = tid >> 6, lane = tid & 63;
  const int g = lane >> 4, li = lane & 15;
  const int bt0 = blockIdx.x * ATILE;
  const int b = bt0 / TT, t0 = bt0 % TT;

  // ---- scores (two C-chunks, partial sums accumulated in p_s) ----
  for (int h = 0; h < 2; ++h) {
    if (h) __syncthreads();
    {  // stage Q chunk: exactly 256 uint4
      const int row = tid >> 5, c8 = tid & 31;
      *(uint4*)(&q_s[row * ACP + c8 * 8]) =
          *(const uint4*)(qkv + (size_t)(bt0 + row) * (3 * CC) + h * ACH + c8 * 8);
    }
    for (int idx = tid; idx < ARWS * 32; idx += 256) {  // stage K chunk
      const int row = idx >> 5, c8 = idx & 31;
      const int src = t0 - (WIN - 1) + row;
      uint4 v = make_uint4(0, 0, 0, 0);
      if (src >= 0 && src < TT)
        v = *(const uint4*)(qkv + (size_t)(b * TT + src) * (3 * CC) + CC + h * ACH + c8 * 8);
      *(uint4*)(&kv_s[row * ACP + c8 * 8]) = v;
    }
    __syncthreads();

#pragma unroll
    for (int tt = 0; tt < 2; ++tt) {
      const int t = wave * 2 + tt;
      // q fragment: li handles elems [li*16, li*16+16)
      uint4 qa = *(const uint4*)(&q_s[t * ACP + li * 16]);
      uint4 qb = *(const uint4*)(&q_s[t * ACP + li * 16 + 8]);
      const unsigned qw[8] = {qa.x, qa.y, qa.z, qa.w, qb.x, qb.y, qb.z, qb.w};
      float2 qf[8];
#pragma unroll
      for (int i = 0; i < 8; ++i) qf[i] = bf2_to_f2(qw[i]);
#pragma unroll
      for (int it = 0; it < 16; ++it) {
        const int j = it * 4 + g;
        if (j >= WSZ) continue;
        const int row = t + j;
        uint4 ka = *(const uint4*)(&kv_s[row * ACP + li * 16]);
        uint4 kb = *(const uint4*)(&kv_s[row * ACP + li * 16 + 8]);
        const unsigned kw[8] = {ka.x, ka.y, ka.z, ka.w, kb.x, kb.y, kb.z, kb.w};
        float s = 0.f;
#pragma unroll
        for (int i = 0; i < 8; ++i) {
          float2 kf = bf2_to_f2(kw[i]);
          s += qf[i].x * kf.x + qf[i].y * kf.y;
        }
        s += __shfl_xor(s, 1); s += __shfl_xor(s, 2);
        s += __shfl_xor(s, 4); s += __shfl_xor(s, 8);
        if (li == 0) {
          if (h) p_s[t][j] += s;
          else   p_s[t][j] = s;
        }
      }
    }
  }
  __syncthreads();

  // ---- softmax over 63 taps (8 rows x 32 threads, 2 j each) ----
  {
    const int row = tid >> 5, l5 = tid & 31;
    const float inv_scale = 0.044194173824159216f;  // 512^-0.5
    const int j0 = l5, j1 = l5 + 32;
    const int src0 = t0 + row + j0 - (WIN - 1);
    const int src1 = t0 + row + j1 - (WIN - 1);
    const bool v0 = (src0 >= 0) && (src0 < TT);                 // j0 <= 31 < 63
    const bool v1 = (j1 < WSZ) && (src1 >= 0) && (src1 < TT);
    float e0 = v0 ? p_s[row][j0] * inv_scale : -INFINITY;
    float e1 = v1 ? p_s[row][j1] * inv_scale : -INFINITY;
    float mx = fmaxf(e0, e1);
    mx = fmaxf(mx, __shfl_xor(mx, 1)); mx = fmaxf(mx, __shfl_xor(mx, 2));
    mx = fmaxf(mx, __shfl_xor(mx, 4)); mx = fmaxf(mx, __shfl_xor(mx, 8));
    mx = fmaxf(mx, __shfl_xor(mx, 16));
    float s0 = v0 ? __expf(e0 - mx) : 0.f;
    float s1 = v1 ? __expf(e1 - mx) : 0.f;
    float sum = s0 + s1;
    sum += __shfl_xor(sum, 1); sum += __shfl_xor(sum, 2);
    sum += __shfl_xor(sum, 4); sum += __shfl_xor(sum, 8);
    sum += __shfl_xor(sum, 16);
    const float rs = 1.f / sum;
    p_s[row][j0] = s0 * rs;
    p_s[row][j1] = s1 * rs;
  }

  // ---- PV (two C-chunks, V staged into kv_s) ----
  for (int h = 0; h < 2; ++h) {
    __syncthreads();
    for (int idx = tid; idx < ARWS * 32; idx += 256) {
      const int row = idx >> 5, c8 = idx & 31;
      const int src = t0 - (WIN - 1) + row;
      uint4 v = make_uint4(0, 0, 0, 0);
      if (src >= 0 && src < TT)
        v = *(const uint4*)(qkv + (size_t)(b * TT + src) * (3 * CC) + 2 * CC + h * ACH + c8 * 8);
      *(uint4*)(&kv_s[row * ACP + c8 * 8]) = v;
    }
    __syncthreads();
    const int t = tid >> 5, l5 = tid & 31;  // 32 lanes x 8 c each
    float2 a[4];
#pragma unroll
    for (int i = 0; i < 4; ++i) a[i] = make_float2(0.f, 0.f);
    for (int j = 0; j < WSZ; ++j) {
      const float p = p_s[t][j];
      const int row = t + j;
      uint4 v = *(const uint4*)(&kv_s[row * ACP + l5 * 8]);
      const unsigned vw[4] = {v.x, v.y, v.z, v.w};
#pragma unroll
      for (int i = 0; i < 4; ++i) {
        float2 vf = bf2_to_f2(vw[i]);
        a[i].x += p * vf.x;
        a[i].y += p * vf.y;
      }
    }
    uint4 o;
    o.x = pack_bf16x2(a[0].x, a[0].y);
    o.y = pack_bf16x2(a[1].x, a[1].y);
    o.z = pack_bf16x2(a[2].x, a[2].y);
    o.w = pack_bf16x2(a[3].x, a[3].y);
    *(uint4*)(out + (size_t)(bt0 + t) * CC + h * ACH + l5 * 8) = o;
  }
}

// ---------------------------------------------------------------------------
extern "C" void kernel_launch(void* const* d_in, const int* in_sizes, int n_in,
                              void* d_out, int out_size, void* d_ws, size_t ws_size,
                              hipStream_t stream) {
  const float* x      = (const float*)d_in[0];
  const float* w_qkv  = (const float*)d_in[1];
  const float* b_qkv  = (const float*)d_in[2];
  const float* w_proj = (const float*)d_in[3];
  const float* b_proj = (const float*)d_in[4];
  float* outp = (float*)d_out;

  ushort* qkv   = (ushort*)d_ws;                    // MM x 1536
  ushort* attn  = qkv + (size_t)MM * 3 * CC;        // MM x 512
  ushort* xb    = attn + (size_t)MM * CC;           // MM x 512
  ushort* wqb   = xb + (size_t)NX;                  // 1536 x 512
  ushort* wpb   = wqb + (size_t)NWQ;                // 512 x 512

  // 0) convert fp32 inputs to bf16
  convert_bf16<<<(NX + NWQ + NWP) / (256 * 8), 256, 0, stream>>>(x, w_qkv, w_proj, xb, wqb, wpb);
  // 1) qkv = x @ w_qkv.T + b_qkv  -> bf16
  {
    dim3 grid((3 * CC) / GBN, MM / GBM);  // 12 x 32
    gemm_nt_mfma<ushort><<<grid, 256, 0, stream>>>(xb, wqb, b_qkv, qkv, MM, 3 * CC, CC);
  }
  // 2) banded attention (bf16 -> bf16)
  attn_tiled<<<MM / ATILE, 256, 0, stream>>>(qkv, attn);
  // 3) out = attn @ w_proj.T + b_proj  -> fp32
  {
    dim3 grid(CC / GBN, MM / GBM);  // 4 x 32
    gemm_nt_mfma<float><<<grid, 256, 0, stream>>>(attn, wpb, b_proj, outp, MM, CC, CC);
  }
}

// Round 4
// 131.029 us; speedup vs baseline: 2.2361x; 1.1014x over previous
//
#include <hip/hip_runtime.h>
#include <math.h>

// LocalAttention: B=2, T=2048, C=512, WINDOW=32
#define BB 2
#define TT 2048
#define CC 512
#define WIN 32
#define WSZ 63            // 2*WIN-1
#define MM (BB * TT)      // 4096

typedef __attribute__((ext_vector_type(8))) short short8;
typedef __attribute__((ext_vector_type(4))) float floatx4;

__device__ inline unsigned short bf16_rn(float f) {
  unsigned u = __builtin_bit_cast(unsigned, f);
  u += 0x7fff + ((u >> 16) & 1);
  return (unsigned short)(u >> 16);
}
__device__ inline unsigned pack_bf16x2(float lo, float hi) {
  return (unsigned)bf16_rn(lo) | ((unsigned)bf16_rn(hi) << 16);
}

// ---------------------------------------------------------------------------
// Pre-convert fp32 inputs -> bf16 (x, w_qkv, w_proj). 8 elems/thread.
// ---------------------------------------------------------------------------
#define NX  (MM * CC)          // 2097152
#define NWQ (3 * CC * CC)      // 786432
#define NWP (CC * CC)          // 262144

__global__ __launch_bounds__(256) void convert_bf16(
    const float* __restrict__ x, const float* __restrict__ wq,
    const float* __restrict__ wp, ushort* __restrict__ xb,
    ushort* __restrict__ wqb, ushort* __restrict__ wpb) {
  const size_t e = ((size_t)blockIdx.x * 256 + threadIdx.x) * 8;
  const float* src;
  ushort* dst;
  size_t off;
  if (e < NX) { src = x; dst = xb; off = e; }
  else if (e < NX + NWQ) { src = wq; dst = wqb; off = e - NX; }
  else { src = wp; dst = wpb; off = e - NX - NWQ; }
  float4 v0 = ((const float4*)(src + off))[0];
  float4 v1 = ((const float4*)(src + off))[1];
  uint4 o;
  o.x = pack_bf16x2(v0.x, v0.y);
  o.y = pack_bf16x2(v0.z, v0.w);
  o.z = pack_bf16x2(v1.x, v1.y);
  o.w = pack_bf16x2(v1.z, v1.w);
  *(uint4*)(dst + off) = o;
}

// ---------------------------------------------------------------------------
// MFMA NT GEMM, all-bf16 A/B: C[m,n] = sum_k A[m,k]*B[n,k] + bias[n]
// 128x128 tile, BK=32, 4 waves (2x2), 4x4 16x16x32 frags per wave.
// ---------------------------------------------------------------------------
#define GBM 128
#define GBN 128
#define GBK 32
#define LDKG 40   // padded k-stride (bf16 elems)

template <typename OT>
__global__ __launch_bounds__(256) void gemm_nt_mfma(
    const ushort* __restrict__ A, const ushort* __restrict__ B,
    const float* __restrict__ bias, OT* __restrict__ C,
    int M, int N, int K) {
  __shared__ __align__(16) ushort As[GBM * LDKG];
  __shared__ __align__(16) ushort Bs[GBN * LDKG];

  const int tid = threadIdx.x;
  const int lane = tid & 63;
  const int wave = tid >> 6;
  const int wm = (wave >> 1) * 64;
  const int wn = (wave & 1) * 64;
  const int m0 = blockIdx.y * GBM;
  const int n0 = blockIdx.x * GBN;
  const int mlane = lane & 15, mquad = lane >> 4;

  floatx4 acc[4][4];
#pragma unroll
  for (int i = 0; i < 4; ++i)
#pragma unroll
    for (int j = 0; j < 4; ++j) acc[i][j] = (floatx4){0.f, 0.f, 0.f, 0.f};

  const int srow = tid >> 1, shalf = tid & 1;  // 16 bf16 per thread per operand

  for (int k0 = 0; k0 < K; k0 += GBK) {
    const uint4* ag = (const uint4*)(A + (size_t)(m0 + srow) * K + k0 + shalf * 16);
    const uint4* bg = (const uint4*)(B + (size_t)(n0 + srow) * K + k0 + shalf * 16);
    uint4 a0 = ag[0], a1 = ag[1];
    uint4 b0 = bg[0], b1 = bg[1];
    __syncthreads();
    *(uint4*)(&As[srow * LDKG + shalf * 16]) = a0;
    *(uint4*)(&As[srow * LDKG + shalf * 16 + 8]) = a1;
    *(uint4*)(&Bs[srow * LDKG + shalf * 16]) = b0;
    *(uint4*)(&Bs[srow * LDKG + shalf * 16 + 8]) = b1;
    __syncthreads();

    short8 af[4], bf[4];
#pragma unroll
    for (int mi = 0; mi < 4; ++mi)
      af[mi] = *(const short8*)(&As[(wm + mi * 16 + mlane) * LDKG + mquad * 8]);
#pragma unroll
    for (int ni = 0; ni < 4; ++ni)
      bf[ni] = *(const short8*)(&Bs[(wn + ni * 16 + mlane) * LDKG + mquad * 8]);
#pragma unroll
    for (int mi = 0; mi < 4; ++mi)
#pragma unroll
      for (int ni = 0; ni < 4; ++ni)
        acc[mi][ni] = __builtin_amdgcn_mfma_f32_16x16x32_bf16(af[mi], bf[ni], acc[mi][ni], 0, 0, 0);
  }

  // epilogue: D row = mquad*4 + r, col = mlane
#pragma unroll
  for (int ni = 0; ni < 4; ++ni) {
    const int n = n0 + wn + ni * 16 + mlane;
    const float bn = bias[n];
#pragma unroll
    for (int mi = 0; mi < 4; ++mi) {
      const int mbase = m0 + wm + mi * 16 + mquad * 4;
#pragma unroll
      for (int r = 0; r < 4; ++r) {
        float val = acc[mi][ni][r] + bn;
        if constexpr (sizeof(OT) == 2)
          ((ushort*)C)[(size_t)(mbase + r) * N + n] = bf16_rn(val);
        else
          ((float*)C)[(size_t)(mbase + r) * N + n] = val;
      }
    }
  }
}

// ---------------------------------------------------------------------------
// MFMA banded attention. Block = 8 tokens (grid 512). Window rows r=0..69
// (src = t0-31+r), padded to 80 = 5 col-tiles of 16.
//  scores: S[16 t][80 r] = Q·K^T via 16x16x32 MFMA, K staged in 2 C-chunks.
//  softmax rows 0..7 (mask j=r-row in [0,63) & src bounds), P -> bf16 LDS
//  (A-frag layout, k padded to 96).
//  PV: Out = P·V via MFMA with V transposed into LDS (vt[c][r]) per C-chunk;
//  scattered 16B global reads (L2-absorbed), conflict-free ds_write_b16.
// LDS plan (bytes): kv[0,42240) q[42240,50688) | vt[0,49152) (union)
//                   s[50688,55808) p[55808,58880)  => 58880 total
// ---------------------------------------------------------------------------
#define ATILE 8
#define NROW 80      // padded window rows (70 real)
#define ACH 256      // C chunk
#define KLD 264      // kv/q row stride (ushorts), 528B: frag reads at 8-cyc floor
#define VLD 96       // vt & p row stride (ushorts)
#define SLD 80       // s row stride (floats)

__global__ __launch_bounds__(256) void attn_mfma(
    const ushort* __restrict__ qkv, ushort* __restrict__ out) {
  __shared__ __align__(16) char smem[58880];
  ushort* kv_s = (ushort*)smem;
  ushort* q_s  = (ushort*)(smem + 42240);
  ushort* vt_s = (ushort*)smem;             // union with kv_s/q_s
  float*  s_s  = (float*)(smem + 50688);
  ushort* p_s  = (ushort*)(smem + 55808);

  const int tid = threadIdx.x;
  const int wave = tid >> 6, lane = tid & 63;
  const int mlane = lane & 15, quad = lane >> 4;
  const int bt0 = blockIdx.x * ATILE;       // 8 | 2048: no batch straddle
  const int b = bt0 / TT, t0 = bt0 % TT;
  const size_t rowbase = (size_t)b * TT * (3 * CC);

  // ---- scores: acc lives across both C-chunks ----
  floatx4 sacc[2];
  sacc[0] = (floatx4){0.f, 0.f, 0.f, 0.f};
  sacc[1] = (floatx4){0.f, 0.f, 0.f, 0.f};
  const int nct = (wave == 0) ? 2 : 1;      // wave0 owns col-tiles 0 and 4

  for (int h = 0; h < 2; ++h) {
    if (h) __syncthreads();
    {  // stage Q chunk: rows 0..7, 256 uint4 total
      const int row = tid >> 5, cb = tid & 31;
      *(uint4*)(&q_s[row * KLD + cb * 8]) =
          *(const uint4*)(&qkv[rowbase + (size_t)(t0 + row) * (3 * CC) + h * ACH + cb * 8]);
    }
    for (int idx = tid; idx < NROW * 32; idx += 256) {  // stage K chunk (80 rows)
      const int r = idx >> 5, cb = idx & 31;
      const int src = t0 - (WIN - 1) + r;
      uint4 v = make_uint4(0, 0, 0, 0);
      if (r < 70 && src >= 0 && src < TT)
        v = *(const uint4*)(&qkv[rowbase + (size_t)src * (3 * CC) + CC + h * ACH + cb * 8]);
      *(uint4*)(&kv_s[r * KLD + cb * 8]) = v;
    }
    __syncthreads();
#pragma unroll
    for (int ks = 0; ks < 8; ++ks) {
      short8 a = *(const short8*)(&q_s[mlane * KLD + ks * 32 + quad * 8]);
#pragma unroll
      for (int s = 0; s < 2; ++s) {
        if (s >= nct) break;
        const int ct = (s == 0) ? wave : 4;
        short8 bf = *(const short8*)(&kv_s[(ct * 16 + mlane) * KLD + ks * 32 + quad * 8]);
        sacc[s] = __builtin_amdgcn_mfma_f32_16x16x32_bf16(a, bf, sacc[s], 0, 0, 0);
      }
    }
  }

  // write S (C/D layout: row = quad*4+r, col = mlane within tile)
#pragma unroll
  for (int s = 0; s < 2; ++s) {
    if (s >= nct) break;
    const int ct = (s == 0) ? wave : 4;
#pragma unroll
    for (int r = 0; r < 4; ++r)
      s_s[(quad * 4 + r) * SLD + ct * 16 + mlane] = sacc[s][r];
  }
  __syncthreads();

  // ---- softmax rows 0..7 (32 lanes per row; cols l5, l5+32, l5+64) ----
  {
    const int row = tid >> 5, l5 = tid & 31;
    const float inv_scale = 0.044194173824159216f;  // 512^-0.5
    const int rr[3] = {l5, l5 + 32, l5 + 64};
    float e[3];
    float mx = -INFINITY;
#pragma unroll
    for (int i = 0; i < 3; ++i) {
      const int r = rr[i];
      const int j = r - row;
      const int src = t0 + r - (WIN - 1);
      const bool valid = (r < NROW) && (j >= 0) && (j < WSZ) && (src >= 0) && (src < TT);
      e[i] = valid ? s_s[row * SLD + r] * inv_scale : -INFINITY;
      mx = fmaxf(mx, e[i]);
    }
    mx = fmaxf(mx, __shfl_xor(mx, 1));  mx = fmaxf(mx, __shfl_xor(mx, 2));
    mx = fmaxf(mx, __shfl_xor(mx, 4));  mx = fmaxf(mx, __shfl_xor(mx, 8));
    mx = fmaxf(mx, __shfl_xor(mx, 16));
    float sum = 0.f;
#pragma unroll
    for (int i = 0; i < 3; ++i) {
      e[i] = (e[i] == -INFINITY) ? 0.f : __expf(e[i] - mx);
      sum += e[i];
    }
    sum += __shfl_xor(sum, 1); sum += __shfl_xor(sum, 2);
    sum += __shfl_xor(sum, 4); sum += __shfl_xor(sum, 8);
    sum += __shfl_xor(sum, 16);
    const float rs = 1.f / sum;
    p_s[row * VLD + rr[0]] = bf16_rn(e[0] * rs);
    p_s[row * VLD + rr[1]] = bf16_rn(e[1] * rs);
    if (l5 < 16) {
      p_s[row * VLD + rr[2]] = bf16_rn(e[2] * rs);
      p_s[row * VLD + 80 + l5] = 0;           // zero k-padding cols 80..95
    }
  }
  __syncthreads();

  // ---- PV per C-chunk: vt[c_local][r] staging + MFMA ----
  for (int h = 0; h < 2; ++h) {
    if (h) __syncthreads();
    // scattered-read transpose: lane owns row r = rg*64+lane; wave owns 8 c-blocks
#pragma unroll
    for (int rg = 0; rg < 2; ++rg) {
      const int r = rg * 64 + lane;
      const bool act = (r < NROW);
      const int src = t0 - (WIN - 1) + r;
      const bool live = act && (r < 70) && (src >= 0) && (src < TT);
#pragma unroll
      for (int i = 0; i < 8; ++i) {
        const int cb = wave * 8 + i;          // 0..31 (c-block of 8 within chunk)
        uint4 v = make_uint4(0, 0, 0, 0);
        if (live)
          v = *(const uint4*)(&qkv[rowbase + (size_t)src * (3 * CC) + 2 * CC + h * ACH + cb * 8]);
        if (act) {
          const unsigned w[4] = {v.x, v.y, v.z, v.w};
#pragma unroll
          for (int ci = 0; ci < 4; ++ci) {
            vt_s[(cb * 8 + 2 * ci) * VLD + r]     = (ushort)(w[ci] & 0xffff);
            vt_s[(cb * 8 + 2 * ci + 1) * VLD + r] = (ushort)(w[ci] >> 16);
          }
        }
      }
    }
    {  // zero vt k-padding cols 80..95 (avoid 0*NaN from stale LDS)
      const uint4 z = make_uint4(0, 0, 0, 0);
      *(uint4*)(&vt_s[tid * VLD + 80]) = z;
      *(uint4*)(&vt_s[tid * VLD + 88]) = z;
    }
    __syncthreads();

    floatx4 oacc[4];
#pragma unroll
    for (int i = 0; i < 4; ++i) oacc[i] = (floatx4){0.f, 0.f, 0.f, 0.f};
#pragma unroll
    for (int ks = 0; ks < 3; ++ks) {
      short8 a = *(const short8*)(&p_s[mlane * VLD + ks * 32 + quad * 8]);
#pragma unroll
      for (int i = 0; i < 4; ++i) {
        const int ctl = wave * 4 + i;
        short8 bf = *(const short8*)(&vt_s[(ctl * 16 + mlane) * VLD + ks * 32 + quad * 8]);
        oacc[i] = __builtin_amdgcn_mfma_f32_16x16x32_bf16(a, bf, oacc[i], 0, 0, 0);
      }
    }
    if (quad < 2) {  // D rows 0..7 are the real tokens
#pragma unroll
      for (int i = 0; i < 4; ++i) {
        const int c = h * ACH + (wave * 4 + i) * 16 + mlane;
#pragma unroll
        for (int r = 0; r < 4; ++r) {
          const int t = quad * 4 + r;
          out[(size_t)(bt0 + t) * CC + c] = bf16_rn(oacc[i][r]);
        }
      }
    }
  }
}

// ---------------------------------------------------------------------------
extern "C" void kernel_launch(void* const* d_in, const int* in_sizes, int n_in,
                              void* d_out, int out_size, void* d_ws, size_t ws_size,
                              hipStream_t stream) {
  const float* x      = (const float*)d_in[0];
  const float* w_qkv  = (const float*)d_in[1];
  const float* b_qkv  = (const float*)d_in[2];
  const float* w_proj = (const float*)d_in[3];
  const float* b_proj = (const float*)d_in[4];
  float* outp = (float*)d_out;

  ushort* qkv   = (ushort*)d_ws;                    // MM x 1536
  ushort* attn  = qkv + (size_t)MM * 3 * CC;        // MM x 512
  ushort* xb    = attn + (size_t)MM * CC;           // MM x 512
  ushort* wqb   = xb + (size_t)NX;                  // 1536 x 512
  ushort* wpb   = wqb + (size_t)NWQ;                // 512 x 512

  // 0) convert fp32 inputs to bf16
  convert_bf16<<<(NX + NWQ + NWP) / (256 * 8), 256, 0, stream>>>(x, w_qkv, w_proj, xb, wqb, wpb);
  // 1) qkv = x @ w_qkv.T + b_qkv  -> bf16
  {
    dim3 grid((3 * CC) / GBN, MM / GBM);  // 12 x 32
    gemm_nt_mfma<ushort><<<grid, 256, 0, stream>>>(xb, wqb, b_qkv, qkv, MM, 3 * CC, CC);
  }
  // 2) banded attention (bf16 -> bf16), MFMA
  attn_mfma<<<MM / ATILE, 256, 0, stream>>>(qkv, attn);
  // 3) out = attn @ w_proj.T + b_proj  -> fp32
  {
    dim3 grid(CC / GBN, MM / GBM);  // 4 x 32
    gemm_nt_mfma<float><<<grid, 256, 0, stream>>>(attn, wpb, b_proj, outp, MM, CC, CC);
  }
}

// Round 5
// 123.220 us; speedup vs baseline: 2.3778x; 1.0634x over previous
//
#include <hip/hip_runtime.h>
#include <math.h>

// LocalAttention: B=2, T=2048, C=512, WINDOW=32
#define BB 2
#define TT 2048
#define CC 512
#define WIN 32
#define WSZ 63            // 2*WIN-1
#define MM (BB * TT)      // 4096

typedef __attribute__((ext_vector_type(8))) short short8;
typedef __attribute__((ext_vector_type(4))) float floatx4;

__device__ inline unsigned short bf16_rn(float f) {
  unsigned u = __builtin_bit_cast(unsigned, f);
  u += 0x7fff + ((u >> 16) & 1);
  return (unsigned short)(u >> 16);
}
__device__ inline unsigned pack_bf16x2(float lo, float hi) {
  return (unsigned)bf16_rn(lo) | ((unsigned)bf16_rn(hi) << 16);
}

// async global->LDS, 16B per lane; LDS dest = wave-uniform base + lane*16
__device__ inline void gll16(const void* g, void* l) {
  __builtin_amdgcn_global_load_lds(
      (const __attribute__((address_space(1))) void*)g,
      (__attribute__((address_space(3))) void*)l, 16, 0, 0);
}

// ---------------------------------------------------------------------------
// Pre-convert fp32 inputs -> bf16 (x, w_qkv, w_proj). 8 elems/thread.
// ---------------------------------------------------------------------------
#define NX  (MM * CC)          // 2097152
#define NWQ (3 * CC * CC)      // 786432
#define NWP (CC * CC)          // 262144

__global__ __launch_bounds__(256) void convert_bf16(
    const float* __restrict__ x, const float* __restrict__ wq,
    const float* __restrict__ wp, ushort* __restrict__ xb,
    ushort* __restrict__ wqb, ushort* __restrict__ wpb) {
  const size_t e = ((size_t)blockIdx.x * 256 + threadIdx.x) * 8;
  const float* src;
  ushort* dst;
  size_t off;
  if (e < NX) { src = x; dst = xb; off = e; }
  else if (e < NX + NWQ) { src = wq; dst = wqb; off = e - NX; }
  else { src = wp; dst = wpb; off = e - NX - NWQ; }
  float4 v0 = ((const float4*)(src + off))[0];
  float4 v1 = ((const float4*)(src + off))[1];
  uint4 o;
  o.x = pack_bf16x2(v0.x, v0.y);
  o.y = pack_bf16x2(v0.z, v0.w);
  o.z = pack_bf16x2(v1.x, v1.y);
  o.w = pack_bf16x2(v1.z, v1.w);
  *(uint4*)(dst + off) = o;
}

// ---------------------------------------------------------------------------
// MFMA NT GEMM, m97-style staging: C[m,n] = sum_k A[m,k]*B[n,k] + bias[n].
// BM=128, BK=32, BN template (128 or 64). 256 threads.
// Unpadded LDS tiles (global_load_lds requires lane-contiguous layout).
// If VT != nullptr and n0 >= VTBASE, the tile is written ONLY transposed to
// VT[n - VTBASE][m] (ushort4 stores, m-contiguous in the fragment).
// ---------------------------------------------------------------------------
#define GBK 32
#define VTBASE 1024

template <int BN, typename OT>
__global__ __launch_bounds__(256) void gemm_nt_mfma(
    const ushort* __restrict__ A, const ushort* __restrict__ B,
    const float* __restrict__ bias, OT* __restrict__ C,
    ushort* __restrict__ VT, int M, int N, int K) {
  constexpr int MI = 4;
  constexpr int NI = (BN == 128) ? 4 : 4;   // BN=64: 4 n-frags, wn=0
  constexpr int MIW = (BN == 128) ? 4 : 2;  // m-frags per wave
  __shared__ __align__(16) ushort As[128 * GBK];
  __shared__ __align__(16) ushort Bs[BN * GBK];

  const int tid = threadIdx.x;
  const int lane = tid & 63;
  const int wave = tid >> 6;
  const int wm = (BN == 128) ? (wave >> 1) * 64 : wave * 32;
  const int wn = (BN == 128) ? (wave & 1) * 64 : 0;
  const int m0 = blockIdx.y * 128;
  const int n0 = blockIdx.x * BN;
  const int mlane = lane & 15, quad = lane >> 4;
  const int lrow = lane >> 2, lcol = (lane & 3) * 8;  // staging: 16 rows x 64B per issue

  floatx4 acc[MIW][NI];
#pragma unroll
  for (int i = 0; i < MIW; ++i)
#pragma unroll
    for (int j = 0; j < NI; ++j) acc[i][j] = (floatx4){0.f, 0.f, 0.f, 0.f};

  for (int k0 = 0; k0 < K; k0 += GBK) {
    __syncthreads();
    // A: 128 rows = 8 issues (4 waves x 2)
#pragma unroll
    for (int q = 0; q < 2; ++q) {
      const int r0 = (q * 4 + wave) * 16;
      gll16(A + (size_t)(m0 + r0 + lrow) * K + k0 + lcol, As + r0 * GBK);
    }
    // B: BN rows = BN/16 issues
#pragma unroll
    for (int q = 0; q < BN / 64; ++q) {
      const int r0 = (q * 4 + wave) * 16;
      gll16(B + (size_t)(n0 + r0 + lrow) * K + k0 + lcol, Bs + r0 * GBK);
    }
    __syncthreads();

    short8 af[MIW], bfr[NI];
#pragma unroll
    for (int mi = 0; mi < MIW; ++mi)
      af[mi] = *(const short8*)(&As[(wm + mi * 16 + mlane) * GBK + quad * 8]);
#pragma unroll
    for (int ni = 0; ni < NI; ++ni)
      bfr[ni] = *(const short8*)(&Bs[(wn + ni * 16 + mlane) * GBK + quad * 8]);
#pragma unroll
    for (int mi = 0; mi < MIW; ++mi)
#pragma unroll
      for (int ni = 0; ni < NI; ++ni)
        acc[mi][ni] = __builtin_amdgcn_mfma_f32_16x16x32_bf16(af[mi], bfr[ni], acc[mi][ni], 0, 0, 0);
  }

  // epilogue: D row = quad*4 + r, col = mlane
  const bool vpath = (VT != nullptr) && (n0 >= VTBASE);
#pragma unroll
  for (int ni = 0; ni < NI; ++ni) {
    const int n = n0 + wn + ni * 16 + mlane;
    const float bn = bias[n];
#pragma unroll
    for (int mi = 0; mi < MIW; ++mi) {
      const int mbase = m0 + wm + mi * 16 + quad * 4;
      if (vpath) {
        ushort4 pk;
        pk.x = bf16_rn(acc[mi][ni][0] + bn);
        pk.y = bf16_rn(acc[mi][ni][1] + bn);
        pk.z = bf16_rn(acc[mi][ni][2] + bn);
        pk.w = bf16_rn(acc[mi][ni][3] + bn);
        *(ushort4*)(VT + (size_t)(n - VTBASE) * M + mbase) = pk;
      } else {
#pragma unroll
        for (int r = 0; r < 4; ++r) {
          float val = acc[mi][ni][r] + bn;
          if constexpr (sizeof(OT) == 2)
            ((ushort*)C)[(size_t)(mbase + r) * N + n] = bf16_rn(val);
          else
            ((float*)C)[(size_t)(mbase + r) * N + n] = val;
        }
      }
    }
  }
}

// ---------------------------------------------------------------------------
// MFMA banded attention. Block = 16 tokens (grid 256). Window rows r=0..79,
// src = t0-32+r (16-elem aligned), tap j = r-1-row, valid j in [0,63).
//  scores: S[16 t][80 r] = Q.K^T, K staged in 2 C-chunks of 256, acc in regs.
//  softmax -> P bf16 in LDS (A-frag layout, k-pad 80..103 zeroed).
//  PV: V read from pre-transposed vT[c][m] (coalesced rows), MFMA per C-chunk.
// LDS: kv[0,42240) q[42240,50688) | vt[0,53248) (union)
//      s[53248,58624) p[58624,61952)
// ---------------------------------------------------------------------------
#define ATILE 16
#define NR 80
#define KLD 264   // 264/8 = 33 granules (odd) -> conflict-free frag reads
#define VLD 104   // 13 granules (odd)
#define SLD 84
#define PLD 104

__global__ __launch_bounds__(256) void attn_mfma(
    const ushort* __restrict__ qkv, const ushort* __restrict__ vT,
    ushort* __restrict__ out) {
  __shared__ __align__(16) char smem[61952];
  ushort* kv_s = (ushort*)smem;
  ushort* q_s  = (ushort*)(smem + 42240);
  ushort* vt_s = (ushort*)smem;             // union
  float*  s_s  = (float*)(smem + 53248);
  ushort* p_s  = (ushort*)(smem + 58624);

  const int tid = threadIdx.x;
  const int wave = tid >> 6, lane = tid & 63;
  const int mlane = lane & 15, quad = lane >> 4;
  const int bt0 = blockIdx.x * ATILE;       // 16 | 2048: no batch straddle
  const int b = bt0 / TT, t0 = bt0 % TT;
  const size_t rowbase = (size_t)b * TT * (3 * CC);

  // ---- scores: acc lives across both C-chunks ----
  floatx4 sacc0 = (floatx4){0.f, 0.f, 0.f, 0.f};
  floatx4 sacc1 = (floatx4){0.f, 0.f, 0.f, 0.f};

  for (int h = 0; h < 2; ++h) {
    if (h) __syncthreads();
#pragma unroll
    for (int i = 0; i < 2; ++i) {  // Q: 16 rows x 32 chunks
      const int idx = tid + 256 * i;
      const int row = idx >> 5, cb = idx & 31;
      *(uint4*)(&q_s[row * KLD + cb * 8]) =
          *(const uint4*)(&qkv[rowbase + (size_t)(t0 + row) * (3 * CC) + h * 256 + cb * 8]);
    }
    for (int idx = tid; idx < NR * 32; idx += 256) {  // K: 80 rows x 32 chunks
      const int r = idx >> 5, cb = idx & 31;
      const int src = t0 - 32 + r;
      uint4 v = make_uint4(0, 0, 0, 0);
      if (src >= 0 && src < TT)
        v = *(const uint4*)(&qkv[rowbase + (size_t)src * (3 * CC) + CC + h * 256 + cb * 8]);
      *(uint4*)(&kv_s[r * KLD + cb * 8]) = v;
    }
    __syncthreads();
#pragma unroll
    for (int ks = 0; ks < 8; ++ks) {
      short8 a = *(const short8*)(&q_s[mlane * KLD + ks * 32 + quad * 8]);
      short8 b0 = *(const short8*)(&kv_s[(wave * 16 + mlane) * KLD + ks * 32 + quad * 8]);
      sacc0 = __builtin_amdgcn_mfma_f32_16x16x32_bf16(a, b0, sacc0, 0, 0, 0);
      if (wave == 0) {
        short8 b1 = *(const short8*)(&kv_s[(64 + mlane) * KLD + ks * 32 + quad * 8]);
        sacc1 = __builtin_amdgcn_mfma_f32_16x16x32_bf16(a, b1, sacc1, 0, 0, 0);
      }
    }
  }

  // write S (D row = quad*4+r = token, col = mlane within col-tile)
#pragma unroll
  for (int r = 0; r < 4; ++r)
    s_s[(quad * 4 + r) * SLD + wave * 16 + mlane] = sacc0[r];
  if (wave == 0) {
#pragma unroll
    for (int r = 0; r < 4; ++r)
      s_s[(quad * 4 + r) * SLD + 64 + mlane] = sacc1[r];
  }
  __syncthreads();

  // ---- softmax: 16 rows x 16 lanes, 5 cols each ----
  {
    const int row = tid >> 4, li = tid & 15;
    const float inv_scale = 0.044194173824159216f;  // 512^-0.5
    float e[5];
    float mx = -INFINITY;
#pragma unroll
    for (int i = 0; i < 5; ++i) {
      const int r = li + 16 * i;
      const int j = r - 1 - row;
      const int src = t0 - 32 + r;
      const bool valid = (j >= 0) && (j < WSZ) && (src >= 0) && (src < TT);
      e[i] = valid ? s_s[row * SLD + r] * inv_scale : -INFINITY;
      mx = fmaxf(mx, e[i]);
    }
    mx = fmaxf(mx, __shfl_xor(mx, 1)); mx = fmaxf(mx, __shfl_xor(mx, 2));
    mx = fmaxf(mx, __shfl_xor(mx, 4)); mx = fmaxf(mx, __shfl_xor(mx, 8));
    float sum = 0.f;
#pragma unroll
    for (int i = 0; i < 5; ++i) {
      e[i] = (e[i] == -INFINITY) ? 0.f : __expf(e[i] - mx);
      sum += e[i];
    }
    sum += __shfl_xor(sum, 1); sum += __shfl_xor(sum, 2);
    sum += __shfl_xor(sum, 4); sum += __shfl_xor(sum, 8);
    const float rs = 1.f / sum;
#pragma unroll
    for (int i = 0; i < 5; ++i)
      p_s[row * PLD + li + 16 * i] = bf16_rn(e[i] * rs);
    if (li < 8) {  // zero k-pad cols 80..103
      p_s[row * PLD + 80 + li] = 0;
      p_s[row * PLD + 88 + li] = 0;
      p_s[row * PLD + 96 + li] = 0;
    }
  }

  // ---- PV per C-chunk: coalesced vT staging + MFMA ----
  const int mcol0 = b * TT + t0 - 32;  // 16-elem aligned; vT has 64-elem guards
  for (int h = 0; h < 2; ++h) {
    __syncthreads();
    for (int idx = tid; idx < 256 * 12; idx += 256) {  // 12 x 16B per c-row
      const int c = idx / 12, ch = idx % 12;
      uint4 v = make_uint4(0, 0, 0, 0);
      if (ch < 10)  // r = ch*8..ch*8+7 (<= 95; rows >= 80 are P-zeroed anyway)
        v = *(const uint4*)(&vT[(size_t)(h * 256 + c) * MM + mcol0 + ch * 8]);
      *(uint4*)(&vt_s[c * VLD + ch * 8]) = v;
    }
    __syncthreads();

    floatx4 oacc[4];
#pragma unroll
    for (int i = 0; i < 4; ++i) oacc[i] = (floatx4){0.f, 0.f, 0.f, 0.f};
#pragma unroll
    for (int ks = 0; ks < 3; ++ks) {
      short8 a = *(const short8*)(&p_s[mlane * PLD + ks * 32 + quad * 8]);
#pragma unroll
      for (int i = 0; i < 4; ++i) {
        short8 bfv = *(const short8*)(&vt_s[((wave * 4 + i) * 16 + mlane) * VLD + ks * 32 + quad * 8]);
        oacc[i] = __builtin_amdgcn_mfma_f32_16x16x32_bf16(a, bfv, oacc[i], 0, 0, 0);
      }
    }
#pragma unroll
    for (int i = 0; i < 4; ++i) {
      const int c = h * 256 + (wave * 4 + i) * 16 + mlane;
#pragma unroll
      for (int r = 0; r < 4; ++r)
        out[(size_t)(bt0 + quad * 4 + r) * CC + c] = bf16_rn(oacc[i][r]);
    }
  }
}

// ---------------------------------------------------------------------------
extern "C" void kernel_launch(void* const* d_in, const int* in_sizes, int n_in,
                              void* d_out, int out_size, void* d_ws, size_t ws_size,
                              hipStream_t stream) {
  const float* x      = (const float*)d_in[0];
  const float* w_qkv  = (const float*)d_in[1];
  const float* b_qkv  = (const float*)d_in[2];
  const float* w_proj = (const float*)d_in[3];
  const float* b_proj = (const float*)d_in[4];
  float* outp = (float*)d_out;

  ushort* qkv   = (ushort*)d_ws;                    // MM x 1536 (V third unused)
  ushort* attn  = qkv + (size_t)MM * 3 * CC;        // MM x 512
  ushort* xb    = attn + (size_t)MM * CC;           // MM x 512
  ushort* wqb   = xb + (size_t)NX;                  // 1536 x 512
  ushort* wpb   = wqb + (size_t)NWQ;                // 512 x 512
  ushort* vTg   = wpb + (size_t)NWP;                // guard(64) + 512 x 4096 + guard(64)
  ushort* vT    = vTg + 64;

  // 0) convert fp32 inputs to bf16
  convert_bf16<<<(NX + NWQ + NWP) / (256 * 8), 256, 0, stream>>>(x, w_qkv, w_proj, xb, wqb, wpb);
  // 1) qkv = x @ w_qkv.T + b_qkv -> Q,K bf16 rows; V written transposed to vT
  {
    dim3 grid((3 * CC) / 128, MM / 128);  // 12 x 32
    gemm_nt_mfma<128, ushort><<<grid, 256, 0, stream>>>(xb, wqb, b_qkv, qkv, vT, MM, 3 * CC, CC);
  }
  // 2) banded attention (bf16 -> bf16), MFMA
  attn_mfma<<<MM / ATILE, 256, 0, stream>>>(qkv, vT, attn);
  // 3) out = attn @ w_proj.T + b_proj -> fp32
  {
    dim3 grid(CC / 64, MM / 128);  // 8 x 32
    gemm_nt_mfma<64, float><<<grid, 256, 0, stream>>>(attn, wpb, b_proj, outp, nullptr, MM, CC, CC);
  }
}

// Round 6
// 120.535 us; speedup vs baseline: 2.4307x; 1.0223x over previous
//
#include <hip/hip_runtime.h>
#include <math.h>

// LocalAttention: B=2, T=2048, C=512, WINDOW=32
#define BB 2
#define TT 2048
#define CC 512
#define WIN 32
#define WSZ 63            // 2*WIN-1
#define MM (BB * TT)      // 4096

typedef __attribute__((ext_vector_type(8))) short short8;
typedef __attribute__((ext_vector_type(4))) float floatx4;

__device__ inline unsigned short bf16_rn(float f) {
  unsigned u = __builtin_bit_cast(unsigned, f);
  u += 0x7fff + ((u >> 16) & 1);
  return (unsigned short)(u >> 16);
}
__device__ inline unsigned pack_bf16x2(float lo, float hi) {
  return (unsigned)bf16_rn(lo) | ((unsigned)bf16_rn(hi) << 16);
}

// async global->LDS, 16B per lane; LDS dest = wave-uniform base + lane*16
__device__ inline void gll16(const void* g, void* l) {
  __builtin_amdgcn_global_load_lds(
      (const __attribute__((address_space(1))) void*)g,
      (__attribute__((address_space(3))) void*)l, 16, 0, 0);
}

// ---------------------------------------------------------------------------
// Pre-convert fp32 inputs -> bf16 (x, w_qkv, w_proj). 8 elems/thread.
// ---------------------------------------------------------------------------
#define NX  (MM * CC)          // 2097152
#define NWQ (3 * CC * CC)      // 786432
#define NWP (CC * CC)          // 262144

__global__ __launch_bounds__(256) void convert_bf16(
    const float* __restrict__ x, const float* __restrict__ wq,
    const float* __restrict__ wp, ushort* __restrict__ xb,
    ushort* __restrict__ wqb, ushort* __restrict__ wpb) {
  const size_t e = ((size_t)blockIdx.x * 256 + threadIdx.x) * 8;
  const float* src;
  ushort* dst;
  size_t off;
  if (e < NX) { src = x; dst = xb; off = e; }
  else if (e < NX + NWQ) { src = wq; dst = wqb; off = e - NX; }
  else { src = wp; dst = wpb; off = e - NX - NWQ; }
  float4 v0 = ((const float4*)(src + off))[0];
  float4 v1 = ((const float4*)(src + off))[1];
  uint4 o;
  o.x = pack_bf16x2(v0.x, v0.y);
  o.y = pack_bf16x2(v0.z, v0.w);
  o.z = pack_bf16x2(v1.x, v1.y);
  o.w = pack_bf16x2(v1.z, v1.w);
  *(uint4*)(dst + off) = o;
}

// ---------------------------------------------------------------------------
// MFMA NT GEMM, m97-style staging (unchanged from round 5).
// If VT != nullptr and n0 >= VTBASE, tile written transposed: VT[n-VTBASE][m].
// ---------------------------------------------------------------------------
#define GBK 32
#define VTBASE 1024

template <int BN, typename OT>
__global__ __launch_bounds__(256) void gemm_nt_mfma(
    const ushort* __restrict__ A, const ushort* __restrict__ B,
    const float* __restrict__ bias, OT* __restrict__ C,
    ushort* __restrict__ VT, int M, int N, int K) {
  constexpr int NI = 4;
  constexpr int MIW = (BN == 128) ? 4 : 2;
  __shared__ __align__(16) ushort As[128 * GBK];
  __shared__ __align__(16) ushort Bs[BN * GBK];

  const int tid = threadIdx.x;
  const int lane = tid & 63;
  const int wave = tid >> 6;
  const int wm = (BN == 128) ? (wave >> 1) * 64 : wave * 32;
  const int wn = (BN == 128) ? (wave & 1) * 64 : 0;
  const int m0 = blockIdx.y * 128;
  const int n0 = blockIdx.x * BN;
  const int mlane = lane & 15, quad = lane >> 4;
  const int lrow = lane >> 2, lcol = (lane & 3) * 8;

  floatx4 acc[MIW][NI];
#pragma unroll
  for (int i = 0; i < MIW; ++i)
#pragma unroll
    for (int j = 0; j < NI; ++j) acc[i][j] = (floatx4){0.f, 0.f, 0.f, 0.f};

  for (int k0 = 0; k0 < K; k0 += GBK) {
    __syncthreads();
#pragma unroll
    for (int q = 0; q < 2; ++q) {
      const int r0 = (q * 4 + wave) * 16;
      gll16(A + (size_t)(m0 + r0 + lrow) * K + k0 + lcol, As + r0 * GBK);
    }
#pragma unroll
    for (int q = 0; q < BN / 64; ++q) {
      const int r0 = (q * 4 + wave) * 16;
      gll16(B + (size_t)(n0 + r0 + lrow) * K + k0 + lcol, Bs + r0 * GBK);
    }
    __syncthreads();

    short8 af[MIW], bfr[NI];
#pragma unroll
    for (int mi = 0; mi < MIW; ++mi)
      af[mi] = *(const short8*)(&As[(wm + mi * 16 + mlane) * GBK + quad * 8]);
#pragma unroll
    for (int ni = 0; ni < NI; ++ni)
      bfr[ni] = *(const short8*)(&Bs[(wn + ni * 16 + mlane) * GBK + quad * 8]);
#pragma unroll
    for (int mi = 0; mi < MIW; ++mi)
#pragma unroll
      for (int ni = 0; ni < NI; ++ni)
        acc[mi][ni] = __builtin_amdgcn_mfma_f32_16x16x32_bf16(af[mi], bfr[ni], acc[mi][ni], 0, 0, 0);
  }

  const bool vpath = (VT != nullptr) && (n0 >= VTBASE);
#pragma unroll
  for (int ni = 0; ni < NI; ++ni) {
    const int n = n0 + wn + ni * 16 + mlane;
    const float bn = bias[n];
#pragma unroll
    for (int mi = 0; mi < MIW; ++mi) {
      const int mbase = m0 + wm + mi * 16 + quad * 4;
      if (vpath) {
        ushort4 pk;
        pk.x = bf16_rn(acc[mi][ni][0] + bn);
        pk.y = bf16_rn(acc[mi][ni][1] + bn);
        pk.z = bf16_rn(acc[mi][ni][2] + bn);
        pk.w = bf16_rn(acc[mi][ni][3] + bn);
        *(ushort4*)(VT + (size_t)(n - VTBASE) * M + mbase) = pk;
      } else {
#pragma unroll
        for (int r = 0; r < 4; ++r) {
          float val = acc[mi][ni][r] + bn;
          if constexpr (sizeof(OT) == 2)
            ((ushort*)C)[(size_t)(mbase + r) * N + n] = bf16_rn(val);
          else
            ((float*)C)[(size_t)(mbase + r) * N + n] = val;
        }
      }
    }
  }
}

// ---------------------------------------------------------------------------
// LDS-free MFMA banded attention. Block = 8 tokens, grid 512, 4 waves.
// Window rows r=0..79, src = t0-32+r; tap j = r-1-t valid in [0,63).
// Q/K/V fragments are loaded DIRECTLY from global (16B/lane, L1/L2-hot);
// only the S->P softmax transform touches LDS (8.7 KB, 2 barriers).
// MFMA m-dim rows 8..15 are don't-care (real but unused tokens / finite pad).
// OOB reads are fault-safe: qkv sits 256 KB into d_ws (front guard) with the
// attn buffer after it (back guard); vT has 64-elem guards. Poison 0xAAAA is
// a finite bf16, and all garbage lands in masked S entries or P=0 columns.
// ---------------------------------------------------------------------------
#define ATILE 8
#define SLD 84    // S row stride (floats)
#define PLD 104   // P row stride (ushorts), 13 granules (odd) -> conflict-free

__global__ __launch_bounds__(256) void attn_mfma(
    const ushort* __restrict__ qkv, const ushort* __restrict__ vT,
    ushort* __restrict__ out) {
  __shared__ __align__(16) float s_s[16 * SLD];   // 5376 B
  __shared__ __align__(16) ushort p_s[16 * PLD];  // 3328 B

  const int tid = threadIdx.x;
  const int wave = tid >> 6, lane = tid & 63;
  const int mlane = lane & 15, quad = lane >> 4;
  const int bt0 = blockIdx.x * ATILE;       // 8 | 2048: no batch straddle
  const int b = bt0 / TT, t0 = bt0 % TT;
  const ushort* qbase = qkv + (size_t)b * TT * (3 * CC);

  // ---- scores: S[16][80] = Q.K^T, direct-global fragments ----
  const ushort* qrow  = qbase + (ptrdiff_t)(t0 + mlane) * (3 * CC);
  const ushort* krow0 = qbase + (ptrdiff_t)(t0 - 32 + wave * 16 + mlane) * (3 * CC) + CC;
  const ushort* krow1 = qbase + (ptrdiff_t)(t0 - 32 + 64 + mlane) * (3 * CC) + CC;
  floatx4 sacc0 = (floatx4){0.f, 0.f, 0.f, 0.f};
  floatx4 sacc1 = (floatx4){0.f, 0.f, 0.f, 0.f};
#pragma unroll
  for (int ks = 0; ks < 16; ++ks) {
    short8 a  = *(const short8*)(qrow + ks * 32 + quad * 8);
    short8 b0 = *(const short8*)(krow0 + ks * 32 + quad * 8);
    sacc0 = __builtin_amdgcn_mfma_f32_16x16x32_bf16(a, b0, sacc0, 0, 0, 0);
    if (wave == 0) {  // wave-uniform branch: wave0 also owns col-tile 4
      short8 b1 = *(const short8*)(krow1 + ks * 32 + quad * 8);
      sacc1 = __builtin_amdgcn_mfma_f32_16x16x32_bf16(a, b1, sacc1, 0, 0, 0);
    }
  }

  // write S (D row = quad*4+r = token row, col = r-index within col-tile)
#pragma unroll
  for (int r = 0; r < 4; ++r)
    s_s[(quad * 4 + r) * SLD + wave * 16 + mlane] = sacc0[r];
  if (wave == 0) {
#pragma unroll
    for (int r = 0; r < 4; ++r)
      s_s[(quad * 4 + r) * SLD + 64 + mlane] = sacc1[r];
  }
  __syncthreads();

  // ---- softmax: 16 rows x 16 lanes, 5 cols each; mask j = r-1-row ----
  {
    const int row = tid >> 4, li = tid & 15;
    const float inv_scale = 0.044194173824159216f;  // 512^-0.5
    float e[5];
    float mx = -INFINITY;
#pragma unroll
    for (int i = 0; i < 5; ++i) {
      const int r = li + 16 * i;
      const int j = r - 1 - row;
      const int src = t0 - 32 + r;
      const bool valid = (j >= 0) && (j < WSZ) && (src >= 0) && (src < TT);
      e[i] = valid ? s_s[row * SLD + r] * inv_scale : -INFINITY;
      mx = fmaxf(mx, e[i]);
    }
    mx = fmaxf(mx, __shfl_xor(mx, 1)); mx = fmaxf(mx, __shfl_xor(mx, 2));
    mx = fmaxf(mx, __shfl_xor(mx, 4)); mx = fmaxf(mx, __shfl_xor(mx, 8));
    float sum = 0.f;
#pragma unroll
    for (int i = 0; i < 5; ++i) {
      e[i] = (e[i] == -INFINITY) ? 0.f : __expf(e[i] - mx);
      sum += e[i];
    }
    sum += __shfl_xor(sum, 1); sum += __shfl_xor(sum, 2);
    sum += __shfl_xor(sum, 4); sum += __shfl_xor(sum, 8);
    const float rs = 1.f / sum;
#pragma unroll
    for (int i = 0; i < 5; ++i)
      p_s[row * PLD + li + 16 * i] = bf16_rn(e[i] * rs);
    if (li < 8) {  // zero k-pad cols 80..103 (PV k-extent is 96)
      p_s[row * PLD + 80 + li] = 0;
      p_s[row * PLD + 88 + li] = 0;
      p_s[row * PLD + 96 + li] = 0;
    }
  }
  __syncthreads();

  // ---- PV: Out[16][512] = P.V, V fragments direct from vT[c][m] ----
  const ptrdiff_t mcol0 = (ptrdiff_t)b * TT + t0 - 32;
#pragma unroll 2
  for (int nt8 = 0; nt8 < 8; ++nt8) {
    const int nt = wave * 8 + nt8;  // c-tile 0..31
    const ushort* vrow = vT + (ptrdiff_t)(nt * 16 + mlane) * MM + mcol0;
    floatx4 o = (floatx4){0.f, 0.f, 0.f, 0.f};
#pragma unroll
    for (int ks = 0; ks < 3; ++ks) {
      short8 a  = *(const short8*)(&p_s[mlane * PLD + ks * 32 + quad * 8]);
      short8 bv = *(const short8*)(vrow + ks * 32 + quad * 8);
      o = __builtin_amdgcn_mfma_f32_16x16x32_bf16(a, bv, o, 0, 0, 0);
    }
    if (quad < 2) {  // D rows 0..7 are the real tokens
#pragma unroll
      for (int r = 0; r < 4; ++r)
        out[(size_t)(bt0 + quad * 4 + r) * CC + nt * 16 + mlane] = bf16_rn(o[r]);
    }
  }
}

// ---------------------------------------------------------------------------
extern "C" void kernel_launch(void* const* d_in, const int* in_sizes, int n_in,
                              void* d_out, int out_size, void* d_ws, size_t ws_size,
                              hipStream_t stream) {
  const float* x      = (const float*)d_in[0];
  const float* w_qkv  = (const float*)d_in[1];
  const float* b_qkv  = (const float*)d_in[2];
  const float* w_proj = (const float*)d_in[3];
  const float* b_proj = (const float*)d_in[4];
  float* outp = (float*)d_out;

  // ws layout (ushorts). 256 KB front guard absorbs attn's src<0 K-reads;
  // attn buffer right after qkv absorbs src>=TT / Q-row overrun reads.
  ushort* base  = (ushort*)d_ws;
  ushort* qkv   = base + 131072;                   // MM x 1536 (V third unused)
  ushort* attn  = qkv + (size_t)MM * 3 * CC;       // MM x 512
  ushort* xb    = attn + (size_t)MM * CC;          // MM x 512
  ushort* wqb   = xb + (size_t)NX;                 // 1536 x 512
  ushort* wpb   = wqb + (size_t)NWQ;               // 512 x 512
  ushort* vTg   = wpb + (size_t)NWP;               // guard(64) + 512 x 4096 + guard(64)
  ushort* vT    = vTg + 64;

  // 0) convert fp32 inputs to bf16
  convert_bf16<<<(NX + NWQ + NWP) / (256 * 8), 256, 0, stream>>>(x, w_qkv, w_proj, xb, wqb, wpb);
  // 1) qkv = x @ w_qkv.T + b_qkv -> Q,K bf16 rows; V written transposed to vT
  {
    dim3 grid((3 * CC) / 128, MM / 128);  // 12 x 32
    gemm_nt_mfma<128, ushort><<<grid, 256, 0, stream>>>(xb, wqb, b_qkv, qkv, vT, MM, 3 * CC, CC);
  }
  // 2) banded attention (bf16 -> bf16), LDS-free MFMA
  attn_mfma<<<MM / ATILE, 256, 0, stream>>>(qkv, vT, attn);
  // 3) out = attn @ w_proj.T + b_proj -> fp32
  {
    dim3 grid(CC / 64, MM / 128);  // 8 x 32
    gemm_nt_mfma<64, float><<<grid, 256, 0, stream>>>(attn, wpb, b_proj, outp, nullptr, MM, CC, CC);
  }
}

// Round 7
// 114.896 us; speedup vs baseline: 2.5500x; 1.0491x over previous
//
#include <hip/hip_runtime.h>
#include <math.h>

// LocalAttention: B=2, T=2048, C=512, WINDOW=32
#define BB 2
#define TT 2048
#define CC 512
#define WIN 32
#define WSZ 63            // 2*WIN-1
#define MM (BB * TT)      // 4096

typedef __attribute__((ext_vector_type(8))) short short8;
typedef __attribute__((ext_vector_type(4))) float floatx4;

__device__ inline unsigned short bf16_rn(float f) {
  unsigned u = __builtin_bit_cast(unsigned, f);
  u += 0x7fff + ((u >> 16) & 1);
  return (unsigned short)(u >> 16);
}
__device__ inline unsigned pack_bf16x2(float lo, float hi) {
  return (unsigned)bf16_rn(lo) | ((unsigned)bf16_rn(hi) << 16);
}

// ---------------------------------------------------------------------------
// Pre-convert fp32 inputs -> bf16 (x, w_qkv, w_proj). 8 elems/thread.
// ---------------------------------------------------------------------------
#define NX  (MM * CC)          // 2097152
#define NWQ (3 * CC * CC)      // 786432
#define NWP (CC * CC)          // 262144

__global__ __launch_bounds__(256) void convert_bf16(
    const float* __restrict__ x, const float* __restrict__ wq,
    const float* __restrict__ wp, ushort* __restrict__ xb,
    ushort* __restrict__ wqb, ushort* __restrict__ wpb) {
  const size_t e = ((size_t)blockIdx.x * 256 + threadIdx.x) * 8;
  const float* src;
  ushort* dst;
  size_t off;
  if (e < NX) { src = x; dst = xb; off = e; }
  else if (e < NX + NWQ) { src = wq; dst = wqb; off = e - NX; }
  else { src = wp; dst = wpb; off = e - NX - NWQ; }
  float4 v0 = ((const float4*)(src + off))[0];
  float4 v1 = ((const float4*)(src + off))[1];
  uint4 o;
  o.x = pack_bf16x2(v0.x, v0.y);
  o.y = pack_bf16x2(v0.z, v0.w);
  o.z = pack_bf16x2(v1.x, v1.y);
  o.w = pack_bf16x2(v1.z, v1.w);
  *(uint4*)(dst + off) = o;
}

// ---------------------------------------------------------------------------
// Barrier-light NT GEMM: C[m,n] = sum_k A[m,k]*B[n,k] + bias[n], K=512 fixed.
// Block = BM x 64. B-panel (64 n x 256 k) staged in LDS once per k-half ->
// only 3 barriers per block, NO per-K-step barrier/drain. A fragments are
// loaded directly from global (L1/L2-hot). 4 waves, each owns BM/4 m-rows
// and the full 64-n range.
// V path (VT != nullptr && n0 >= 1024): tile is bias-added, packed to bf16,
// transposed through LDS, and written as coalesced 256B rows of VT[n][m].
// ---------------------------------------------------------------------------
#define PSTR 264   // B-panel k-stride (elems); 528B rows -> 2-way banked frag reads
#define VSTR 136   // V-transpose m-stride (elems); 16B-aligned rows, odd granules

template <int BM, typename OT>
__global__ __launch_bounds__(256) void gemm_panel(
    const ushort* __restrict__ A, const ushort* __restrict__ B,
    const float* __restrict__ bias, OT* __restrict__ C,
    ushort* __restrict__ VT, int M, int N) {
  constexpr int MIW = BM / 64;                    // m-frags per wave (2 or 1)
  __shared__ __align__(16) ushort Bs[64 * PSTR];  // 33792 B; Vt aliases below

  const int tid = threadIdx.x;
  const int lane = tid & 63;
  const int wave = tid >> 6;
  const int m0 = blockIdx.y * BM;
  const int n0 = blockIdx.x * 64;
  const int wm = wave * (BM / 4);
  const int mlane = lane & 15, quad = lane >> 4;

  floatx4 acc[MIW][4];
#pragma unroll
  for (int i = 0; i < MIW; ++i)
#pragma unroll
    for (int j = 0; j < 4; ++j) acc[i][j] = (floatx4){0.f, 0.f, 0.f, 0.f};

  for (int h = 0; h < 2; ++h) {
    if (h) __syncthreads();
    // stage B panel half: 64 rows x 256 k = 2048 uint4, coalesced
#pragma unroll
    for (int i = 0; i < 8; ++i) {
      const int idx = tid + 256 * i;
      const int r = idx >> 5, kc = (idx & 31) * 8;
      *(uint4*)(&Bs[r * PSTR + kc]) =
          *(const uint4*)(B + (size_t)(n0 + r) * CC + h * 256 + kc);
    }
    __syncthreads();
#pragma unroll
    for (int ks = 0; ks < 8; ++ks) {
      short8 bfr[4];
#pragma unroll
      for (int ni = 0; ni < 4; ++ni)
        bfr[ni] = *(const short8*)(&Bs[(ni * 16 + mlane) * PSTR + ks * 32 + quad * 8]);
#pragma unroll
      for (int mi = 0; mi < MIW; ++mi) {
        short8 af = *(const short8*)(
            A + (size_t)(m0 + wm + mi * 16 + mlane) * CC + h * 256 + ks * 32 + quad * 8);
#pragma unroll
        for (int ni = 0; ni < 4; ++ni)
          acc[mi][ni] = __builtin_amdgcn_mfma_f32_16x16x32_bf16(af, bfr[ni], acc[mi][ni], 0, 0, 0);
      }
    }
  }

  // epilogue: D row = quad*4 + r (m), col = mlane (n)
  const bool vpath = (VT != nullptr) && (n0 >= 1024);
  if (!vpath) {
#pragma unroll
    for (int ni = 0; ni < 4; ++ni) {
      const int n = n0 + ni * 16 + mlane;
      const float bn = bias[n];
#pragma unroll
      for (int mi = 0; mi < MIW; ++mi) {
        const int mbase = m0 + wm + mi * 16 + quad * 4;
#pragma unroll
        for (int r = 0; r < 4; ++r) {
          float val = acc[mi][ni][r] + bn;
          if constexpr (sizeof(OT) == 2)
            ((ushort*)C)[(size_t)(mbase + r) * N + n] = bf16_rn(val);
          else
            ((float*)C)[(size_t)(mbase + r) * N + n] = val;
        }
      }
    }
  } else if constexpr (BM == 128) {
    // transpose through LDS, then coalesced VT[n][m] row writes
    ushort* Vt = Bs;  // alias; 64 x VSTR = 17408 B
    __syncthreads();
#pragma unroll
    for (int ni = 0; ni < 4; ++ni) {
      const int n_l = ni * 16 + mlane;
      const float bn = bias[n0 + n_l];
#pragma unroll
      for (int mi = 0; mi < MIW; ++mi) {
        const int m_l = wm + mi * 16 + quad * 4;
        ushort4 pk;
        pk.x = bf16_rn(acc[mi][ni][0] + bn);
        pk.y = bf16_rn(acc[mi][ni][1] + bn);
        pk.z = bf16_rn(acc[mi][ni][2] + bn);
        pk.w = bf16_rn(acc[mi][ni][3] + bn);
        *(ushort4*)(&Vt[n_l * VSTR + m_l]) = pk;
      }
    }
    __syncthreads();
#pragma unroll
    for (int i = 0; i < 4; ++i) {  // 64 rows x 16 uint4
      const int idx = tid + 256 * i;
      const int n_l = idx >> 4, mo = (idx & 15) * 8;
      *(uint4*)(VT + (size_t)(n0 - 1024 + n_l) * M + m0 + mo) =
          *(const uint4*)(&Vt[n_l * VSTR + mo]);
    }
  }
}

// ---------------------------------------------------------------------------
// LDS-free MFMA banded attention (unchanged from round 6). Block = 8 tokens,
// grid 512. Q/K/V fragments direct from global; only softmax S->P uses LDS.
// OOB reads fault-safe via ws guards; garbage lands in masked/P=0 positions.
// ---------------------------------------------------------------------------
#define ATILE 8
#define SLD 84    // S row stride (floats)
#define PLD 104   // P row stride (ushorts), odd granules -> conflict-free

__global__ __launch_bounds__(256) void attn_mfma(
    const ushort* __restrict__ qkv, const ushort* __restrict__ vT,
    ushort* __restrict__ out) {
  __shared__ __align__(16) float s_s[16 * SLD];
  __shared__ __align__(16) ushort p_s[16 * PLD];

  const int tid = threadIdx.x;
  const int wave = tid >> 6, lane = tid & 63;
  const int mlane = lane & 15, quad = lane >> 4;
  const int bt0 = blockIdx.x * ATILE;
  const int b = bt0 / TT, t0 = bt0 % TT;
  const ushort* qbase = qkv + (size_t)b * TT * (3 * CC);

  const ushort* qrow  = qbase + (ptrdiff_t)(t0 + mlane) * (3 * CC);
  const ushort* krow0 = qbase + (ptrdiff_t)(t0 - 32 + wave * 16 + mlane) * (3 * CC) + CC;
  const ushort* krow1 = qbase + (ptrdiff_t)(t0 - 32 + 64 + mlane) * (3 * CC) + CC;
  floatx4 sacc0 = (floatx4){0.f, 0.f, 0.f, 0.f};
  floatx4 sacc1 = (floatx4){0.f, 0.f, 0.f, 0.f};
#pragma unroll
  for (int ks = 0; ks < 16; ++ks) {
    short8 a  = *(const short8*)(qrow + ks * 32 + quad * 8);
    short8 b0 = *(const short8*)(krow0 + ks * 32 + quad * 8);
    sacc0 = __builtin_amdgcn_mfma_f32_16x16x32_bf16(a, b0, sacc0, 0, 0, 0);
    if (wave == 0) {
      short8 b1 = *(const short8*)(krow1 + ks * 32 + quad * 8);
      sacc1 = __builtin_amdgcn_mfma_f32_16x16x32_bf16(a, b1, sacc1, 0, 0, 0);
    }
  }

#pragma unroll
  for (int r = 0; r < 4; ++r)
    s_s[(quad * 4 + r) * SLD + wave * 16 + mlane] = sacc0[r];
  if (wave == 0) {
#pragma unroll
    for (int r = 0; r < 4; ++r)
      s_s[(quad * 4 + r) * SLD + 64 + mlane] = sacc1[r];
  }
  __syncthreads();

  {
    const int row = tid >> 4, li = tid & 15;
    const float inv_scale = 0.044194173824159216f;  // 512^-0.5
    float e[5];
    float mx = -INFINITY;
#pragma unroll
    for (int i = 0; i < 5; ++i) {
      const int r = li + 16 * i;
      const int j = r - 1 - row;
      const int src = t0 - 32 + r;
      const bool valid = (j >= 0) && (j < WSZ) && (src >= 0) && (src < TT);
      e[i] = valid ? s_s[row * SLD + r] * inv_scale : -INFINITY;
      mx = fmaxf(mx, e[i]);
    }
    mx = fmaxf(mx, __shfl_xor(mx, 1)); mx = fmaxf(mx, __shfl_xor(mx, 2));
    mx = fmaxf(mx, __shfl_xor(mx, 4)); mx = fmaxf(mx, __shfl_xor(mx, 8));
    float sum = 0.f;
#pragma unroll
    for (int i = 0; i < 5; ++i) {
      e[i] = (e[i] == -INFINITY) ? 0.f : __expf(e[i] - mx);
      sum += e[i];
    }
    sum += __shfl_xor(sum, 1); sum += __shfl_xor(sum, 2);
    sum += __shfl_xor(sum, 4); sum += __shfl_xor(sum, 8);
    const float rs = 1.f / sum;
#pragma unroll
    for (int i = 0; i < 5; ++i)
      p_s[row * PLD + li + 16 * i] = bf16_rn(e[i] * rs);
    if (li < 8) {
      p_s[row * PLD + 80 + li] = 0;
      p_s[row * PLD + 88 + li] = 0;
      p_s[row * PLD + 96 + li] = 0;
    }
  }
  __syncthreads();

  const ptrdiff_t mcol0 = (ptrdiff_t)b * TT + t0 - 32;
#pragma unroll 2
  for (int nt8 = 0; nt8 < 8; ++nt8) {
    const int nt = wave * 8 + nt8;
    const ushort* vrow = vT + (ptrdiff_t)(nt * 16 + mlane) * MM + mcol0;
    floatx4 o = (floatx4){0.f, 0.f, 0.f, 0.f};
#pragma unroll
    for (int ks = 0; ks < 3; ++ks) {
      short8 a  = *(const short8*)(&p_s[mlane * PLD + ks * 32 + quad * 8]);
      short8 bv = *(const short8*)(vrow + ks * 32 + quad * 8);
      o = __builtin_amdgcn_mfma_f32_16x16x32_bf16(a, bv, o, 0, 0, 0);
    }
    if (quad < 2) {
#pragma unroll
      for (int r = 0; r < 4; ++r)
        out[(size_t)(bt0 + quad * 4 + r) * CC + nt * 16 + mlane] = bf16_rn(o[r]);
    }
  }
}

// ---------------------------------------------------------------------------
extern "C" void kernel_launch(void* const* d_in, const int* in_sizes, int n_in,
                              void* d_out, int out_size, void* d_ws, size_t ws_size,
                              hipStream_t stream) {
  const float* x      = (const float*)d_in[0];
  const float* w_qkv  = (const float*)d_in[1];
  const float* b_qkv  = (const float*)d_in[2];
  const float* w_proj = (const float*)d_in[3];
  const float* b_proj = (const float*)d_in[4];
  float* outp = (float*)d_out;

  // ws layout (ushorts). 256 KB front guard absorbs attn's src<0 K-reads;
  // attn buffer right after qkv absorbs src>=TT / Q-row overrun reads.
  ushort* base  = (ushort*)d_ws;
  ushort* qkv   = base + 131072;                   // MM x 1536 (V third unused)
  ushort* attn  = qkv + (size_t)MM * 3 * CC;       // MM x 512
  ushort* xb    = attn + (size_t)MM * CC;          // MM x 512
  ushort* wqb   = xb + (size_t)NX;                 // 1536 x 512
  ushort* wpb   = wqb + (size_t)NWQ;               // 512 x 512
  ushort* vTg   = wpb + (size_t)NWP;               // guard(64) + 512 x 4096 + guard(64)
  ushort* vT    = vTg + 64;

  // 0) convert fp32 inputs to bf16
  convert_bf16<<<(NX + NWQ + NWP) / (256 * 8), 256, 0, stream>>>(x, w_qkv, w_proj, xb, wqb, wpb);
  // 1) qkv = x @ w_qkv.T + b_qkv -> Q,K bf16 rows; V written transposed to vT
  {
    dim3 grid((3 * CC) / 64, MM / 128);  // 24 x 32 = 768 blocks
    gemm_panel<128, ushort><<<grid, 256, 0, stream>>>(xb, wqb, b_qkv, qkv, vT, MM, 3 * CC);
  }
  // 2) banded attention (bf16 -> bf16), LDS-free MFMA
  attn_mfma<<<MM / ATILE, 256, 0, stream>>>(qkv, vT, attn);
  // 3) out = attn @ w_proj.T + b_proj -> fp32
  {
    dim3 grid(CC / 64, MM / 64);  // 8 x 64 = 512 blocks
    gemm_panel<64, float><<<grid, 256, 0, stream>>>(attn, wpb, b_proj, outp, nullptr, MM, CC);
  }
}